// Round 4
// baseline (787.730 us; speedup 1.0000x reference)
//
#include <hip/hip_runtime.h>

#define Bn 16
#define Nn 1024
#define DIN 32
#define DZ 64
#define Fc 3
#define Pp 19
#define PPAD 20
#define Ee 171
#define ITERS 50
#define INV_SCALE (19.0f/1024.0f)
#define CHUNK 64
#define PF 4
#define PFK 8

// workspace offsets (in floats)
#define OFF_WPROJ 0         // [B][F][N][PPAD]  983040
#define OFF_FFULL 983040    // [B][N][F]        49152
#define OFF_FLAT  1033216   // [B][F][19]       912
#define OFF_UBUF  1034128   // [B][57]          912
#define OFF_BVALS 1035040   // [B][N][F]        49152   -- zero region start
#define OFF_ZACC  1084192   // [B][64]          1024
#define OFF_KHAT  1085216   // [B][F][16][19]   14592
#define OFF_SRC   1099808   // [B][F][16]       768
#define ZERO_FLOATS 65536   // BVALS+ZACC+KHAT+SRC contiguous
#define OFF_TPART 1100576   // [B*F][16 chunks][16 p][1024 j]  12582912 floats (48 MB)
#define NEED_FLOATS (OFF_TPART + 48*16*16*1024)

// ---------------- scatter boundary_vals (parallel, deterministic last-wins) ----------------
__global__ __launch_bounds__(1024) void k_scatter(const int* __restrict__ nodes,
                                                  const float* __restrict__ bvals,
                                                  float* __restrict__ bfull) {
  __shared__ int sn[1024];
  int tid = threadIdx.x;
  sn[tid] = nodes[tid];
  __syncthreads();
  int b = tid >> 6, j = tid & 63;
  int node = sn[tid];
  bool win = true;
  for (int j2 = j + 1; j2 < 64; j2++)
    if (sn[(b << 6) | j2] == node) { win = false; break; }
  if (win) {
    #pragma unroll
    for (int f = 0; f < Fc; f++)
      bfull[((size_t)b*Nn + node)*Fc + f] = bvals[(size_t)tid*Fc + f];
  }
}

// ---------------- encoder + POU softmax + f_full + zacc partials ----------------
__global__ __launch_bounds__(128) void k_encode(
    const float* __restrict__ x, const float* __restrict__ Wenc, const float* __restrict__ benc,
    const float* __restrict__ Wsrc, const float* __restrict__ bsrc, const float* __restrict__ Wpou,
    const float* __restrict__ bfull, float* __restrict__ wproj, float* __restrict__ ffull,
    float* __restrict__ zacc) {
  __shared__ float sWenc[DIN*DZ];
  __shared__ float sWpou[DZ*57];
  __shared__ float sWsrc[DZ*Fc];
  int tid = threadIdx.x;
  for (int t = tid; t < DIN*DZ; t += 128) sWenc[t] = Wenc[t];
  for (int t = tid; t < DZ*57; t += 128) sWpou[t] = Wpou[t];
  for (int t = tid; t < DZ*Fc; t += 128) sWsrc[t] = Wsrc[t];
  __syncthreads();
  int g = blockIdx.x*128 + tid;         // b*N + i
  int b = g >> 10, i = g & 1023;
  float xr[DIN];
  const float* xp = x + (size_t)g*DIN;
  #pragma unroll
  for (int k = 0; k < DIN; k += 4) {
    float4 t4 = *(const float4*)(xp + k);
    xr[k] = t4.x; xr[k+1] = t4.y; xr[k+2] = t4.z; xr[k+3] = t4.w;
  }
  float l[57];
  #pragma unroll
  for (int o = 0; o < 57; o++) l[o] = 0.f;
  float ff[3] = {bsrc[0], bsrc[1], bsrc[2]};
  int lane = tid & 63;
  for (int d = 0; d < DZ; d++) {
    float zd = benc[d];
    #pragma unroll
    for (int k = 0; k < DIN; k++) zd = fmaf(xr[k], sWenc[k*DZ + d], zd);
    zd = tanhf(zd);
    #pragma unroll
    for (int o = 0; o < 57; o++) l[o] = fmaf(zd, sWpou[d*57 + o], l[o]);
    #pragma unroll
    for (int f = 0; f < Fc; f++) ff[f] = fmaf(zd, sWsrc[d*Fc + f], ff[f]);
    float zs = zd;
    #pragma unroll
    for (int off = 32; off > 0; off >>= 1) zs += __shfl_xor(zs, off, 64);
    if (lane == 0) atomicAdd(&zacc[b*DZ + d], zs);
  }
  #pragma unroll
  for (int f = 0; f < Fc; f++) ffull[(size_t)g*Fc + f] = ff[f];
  #pragma unroll
  for (int f = 0; f < Fc; f++) {
    float bv = bfull[(size_t)g*Fc + f];
    l[16*3+f] += bv; l[17*3+f] += bv; l[18*3+f] += bv;
  }
  #pragma unroll
  for (int f = 0; f < Fc; f++) {
    float m = l[f];
    #pragma unroll
    for (int p = 1; p < Pp; p++) m = fmaxf(m, l[p*3+f]);
    float ex[Pp]; float s = 0.f;
    #pragma unroll
    for (int p = 0; p < Pp; p++) { ex[p] = __expf(l[p*3+f] - m); s += ex[p]; }
    float inv = 1.f / s;
    float* wp = wproj + ((size_t)(b*Fc + f)*Nn + i)*PPAD;
    #pragma unroll
    for (int p = 0; p < Pp; p++) wp[p] = ex[p]*inv;
  }
}

// ---------------- f_latent[b,f,q] = (1/scale) sum_i W[q,i] f_full[i,f] ----------------
__global__ __launch_bounds__(256) void k_flat(const float* __restrict__ wproj,
                                              const float* __restrict__ ffull,
                                              float* __restrict__ flat) {
  int bf = blockIdx.x;                 // b*3+f
  int b = bf / 3, f = bf % 3;
  float acc[Pp];
  #pragma unroll
  for (int q = 0; q < Pp; q++) acc[q] = 0.f;
  for (int i = threadIdx.x; i < Nn; i += 256) {
    float fv = ffull[((size_t)b*Nn + i)*Fc + f];
    const float* row = wproj + ((size_t)bf*Nn + i)*PPAD;
    #pragma unroll
    for (int q = 0; q < Pp; q++) acc[q] = fmaf(row[q], fv, acc[q]);
  }
  #pragma unroll
  for (int q = 0; q < Pp; q++) {
    float v = acc[q];
    #pragma unroll
    for (int off = 32; off > 0; off >>= 1) v += __shfl_xor(v, off, 64);
    acc[q] = v;
  }
  __shared__ float red[4][Pp];
  int wave = threadIdx.x >> 6, lane = threadIdx.x & 63;
  if (lane == 0) {
    #pragma unroll
    for (int q = 0; q < Pp; q++) red[wave][q] = acc[q];
  }
  __syncthreads();
  if (threadIdx.x < Pp) {
    float s = red[0][threadIdx.x] + red[1][threadIdx.x] + red[2][threadIdx.x] + red[3][threadIdx.x];
    flat[bf*Pp + threadIdx.x] = s * INV_SCALE;
  }
}

// ---------------- K pass: T_chunk[p, j] = sum_i W[p,i] K[i,j]  (coalesced float4 out) ----------------
__global__ __launch_bounds__(256, 3) void k_projT(
    const float* __restrict__ Kl, const float* __restrict__ wproj,
    float* __restrict__ tpart) {
  __shared__ float sW[16*CHUNK];       // sW[p*64 + r] = W[p, i0+r]
  int chunk = blockIdx.x;              // 16 i-chunks of 64
  int bf = blockIdx.y;                 // 48
  int i0 = chunk * CHUNK;
  const float* Kb = Kl + (size_t)bf*Nn*Nn + (size_t)i0*Nn;
  const float* Wrow0 = wproj + ((size_t)bf*Nn + i0)*PPAD;
  int tid = threadIdx.x;
  for (int t = tid; t < 16*CHUNK; t += 256) {
    int r = t & (CHUNK-1), p = t >> 6;
    sW[p*CHUNK + r] = Wrow0[r*PPAD + p];
  }
  __syncthreads();
  int j0 = tid * 4;
  float4 acc[16];
  #pragma unroll
  for (int p = 0; p < 16; p++) { acc[p].x = 0.f; acc[p].y = 0.f; acc[p].z = 0.f; acc[p].w = 0.f; }
  const float* kp = Kb + j0;
  float4 kbuf[PFK];
  #pragma unroll
  for (int s = 0; s < PFK; s++) kbuf[s] = *(const float4*)(kp + (size_t)s*Nn);
  for (int ii = 0; ii < CHUNK; ii += PFK) {
    #pragma unroll
    for (int s = 0; s < PFK; s++) {
      float4 k4 = kbuf[s];
      int nxt = (ii + PFK + s) & (CHUNK - 1);   // tail wraps to rows 0..7 (L2-hot, harmless)
      kbuf[s] = *(const float4*)(kp + (size_t)nxt*Nn);
      const float* wrow = &sW[ii + s];           // wave-uniform -> LDS broadcast
      #pragma unroll
      for (int p = 0; p < 16; p++) {
        float wv = wrow[p*CHUNK];
        acc[p].x = fmaf(wv, k4.x, acc[p].x);
        acc[p].y = fmaf(wv, k4.y, acc[p].y);
        acc[p].z = fmaf(wv, k4.z, acc[p].z);
        acc[p].w = fmaf(wv, k4.w, acc[p].w);
      }
    }
  }
  float* tp = tpart + ((size_t)(bf*16 + chunk)*16)*Nn + j0;
  #pragma unroll
  for (int p = 0; p < 16; p++) *(float4*)(tp + (size_t)p*Nn) = acc[p];
}

// ---------------- M pass: src[p] = (1/s) sum_i W[p,i] (M[i,:].Wv)  ----------------
__global__ __launch_bounds__(256, 3) void k_projM(
    const float* __restrict__ Ml, const float* __restrict__ wproj,
    const float* __restrict__ flat, float* __restrict__ srca) {
  __shared__ float sW[16*CHUNK];
  int chunk = blockIdx.x;
  int bf = blockIdx.y;
  int i0 = chunk * CHUNK;
  const float* Mb = Ml + (size_t)bf*Nn*Nn + (size_t)i0*Nn;
  const float* Wp = wproj + (size_t)bf*Nn*PPAD;
  const float* Wrow0 = Wp + (size_t)i0*PPAD;
  int tid = threadIdx.x;
  for (int t = tid; t < 16*CHUNK; t += 256) {
    int r = t & (CHUNK-1), p = t >> 6;
    sW[p*CHUNK + r] = Wrow0[r*PPAD + p];
  }
  // v[r] = sum_q W[q, j0+r] * fl[q]
  float fl[Pp];
  #pragma unroll
  for (int q = 0; q < Pp; q++) fl[q] = flat[bf*Pp + q];
  int j0 = tid * 4;
  float v0, v1, v2, v3;
  {
    float vv[4];
    #pragma unroll
    for (int r = 0; r < 4; r++) {
      const float* row = Wp + (size_t)(j0 + r)*PPAD;
      float s = 0.f;
      #pragma unroll
      for (int q = 0; q < Pp; q++) s = fmaf(row[q], fl[q], s);
      vv[r] = s;
    }
    v0 = vv[0]; v1 = vv[1]; v2 = vv[2]; v3 = vv[3];
  }
  __syncthreads();
  float sa[16];
  #pragma unroll
  for (int p = 0; p < 16; p++) sa[p] = 0.f;
  const float* mp = Mb + j0;
  float4 mbuf[PFK];
  #pragma unroll
  for (int s = 0; s < PFK; s++) mbuf[s] = *(const float4*)(mp + (size_t)s*Nn);
  for (int ii = 0; ii < CHUNK; ii += PFK) {
    #pragma unroll
    for (int s = 0; s < PFK; s++) {
      float4 m4 = mbuf[s];
      int nxt = (ii + PFK + s) & (CHUNK - 1);
      mbuf[s] = *(const float4*)(mp + (size_t)nxt*Nn);
      float tm = m4.x*v0 + m4.y*v1 + m4.z*v2 + m4.w*v3;
      const float* wrow = &sW[ii + s];
      #pragma unroll
      for (int p = 0; p < 16; p++) sa[p] = fmaf(wrow[p*CHUNK], tm, sa[p]);
    }
  }
  int lane = tid & 63;
  #pragma unroll
  for (int p = 0; p < 16; p++) {
    float vq = sa[p];
    #pragma unroll
    for (int off = 32; off > 0; off >>= 1) vq += __shfl_xor(vq, off, 64);
    sa[p] = vq;
  }
  if (lane == 0) {
    #pragma unroll
    for (int p = 0; p < 16; p++) atomicAdd(&srca[bf*16 + p], sa[p] * INV_SCALE);
  }
}

// ---------------- khat[p][q] = INV_SCALE * sum_j (sum_c Tpart[c][p][j]) * W[q][j] ----------------
__global__ __launch_bounds__(256) void k_khat(const float* __restrict__ tpart,
                                              const float* __restrict__ wproj,
                                              float* __restrict__ khat) {
  __shared__ float sT[16*64];          // [p][r]
  __shared__ float sWq[64*PPAD];       // [r][q]
  int jb = blockIdx.x, bf = blockIdx.y;
  int tid = threadIdx.x;
  {
    int id = tid * 4;                  // 4 consecutive floats of one p-row
    int p = id >> 6;
    int r = id & 63;
    const float* base = tpart + ((size_t)(bf*16)*16 + p)*Nn + jb*64 + r;
    float4 s4 = make_float4(0.f, 0.f, 0.f, 0.f);
    #pragma unroll 4
    for (int c = 0; c < 16; c++) {
      float4 t4 = *(const float4*)(base + (size_t)c*16*Nn);
      s4.x += t4.x; s4.y += t4.y; s4.z += t4.z; s4.w += t4.w;
    }
    *(float4*)&sT[p*64 + r] = s4;
  }
  const float* wsrc = wproj + ((size_t)bf*Nn + jb*64)*PPAD;   // 1280 contiguous floats
  for (int t = tid; t < 64*PPAD; t += 256) sWq[t] = wsrc[t];
  __syncthreads();
  for (int o = tid; o < 16*Pp; o += 256) {
    int p = o / Pp, q = o - p*Pp;
    float s = 0.f;
    #pragma unroll
    for (int r = 0; r < 64; r++) s = fmaf(sT[p*64 + r], sWq[r*PPAD + q], s);
    atomicAdd(&khat[(bf*16 + p)*Pp + q], s * INV_SCALE);
  }
}

// ---------------- fallback heavy pass (round-1 version) if workspace too small ----------------
__global__ __launch_bounds__(256, 1) void k_project_fb(
    const float* __restrict__ Kl, const float* __restrict__ Ml,
    const float* __restrict__ wproj, const float* __restrict__ flat,
    float* __restrict__ khat, float* __restrict__ srca) {
  __shared__ float sW[16*CHUNK];
  int chunk = blockIdx.x;
  int bf = blockIdx.y;
  int i0 = chunk * CHUNK;
  const float* Kb = Kl + (size_t)bf*Nn*Nn + (size_t)i0*Nn;
  const float* Mb = Ml + (size_t)bf*Nn*Nn + (size_t)i0*Nn;
  const float* Wp = wproj + (size_t)bf*Nn*PPAD;
  const float* Wrow0 = Wp + (size_t)i0*PPAD;
  int tid = threadIdx.x;
  for (int t = tid; t < 16*CHUNK; t += 256) {
    int r = t & (CHUNK-1), p = t >> 6;
    sW[p*CHUNK + r] = Wrow0[r*PPAD + p];
  }
  float fl[Pp];
  #pragma unroll
  for (int q = 0; q < Pp; q++) fl[q] = flat[bf*Pp + q];
  int j0 = tid * 4;
  float v[4];
  #pragma unroll
  for (int r = 0; r < 4; r++) {
    const float* row = Wp + (size_t)(j0 + r)*PPAD;
    float s = 0.f;
    #pragma unroll
    for (int q = 0; q < Pp; q++) s = fmaf(row[q], fl[q], s);
    v[r] = s;
  }
  __syncthreads();
  float4 acc[16];
  float sa[16];
  #pragma unroll
  for (int p = 0; p < 16; p++) {
    acc[p].x = 0.f; acc[p].y = 0.f; acc[p].z = 0.f; acc[p].w = 0.f;
    sa[p] = 0.f;
  }
  const float* kp = Kb + j0;
  const float* mp = Mb + j0;
  float4 kbuf[PF], mbuf[PF];
  #pragma unroll
  for (int s = 0; s < PF; s++) {
    kbuf[s] = *(const float4*)(kp + (size_t)s*Nn);
    mbuf[s] = *(const float4*)(mp + (size_t)s*Nn);
  }
  for (int ii = 0; ii < CHUNK; ii += PF) {
    #pragma unroll
    for (int s = 0; s < PF; s++) {
      float4 k4 = kbuf[s], m4 = mbuf[s];
      int nxt = (ii + PF + s) & (CHUNK - 1);
      kbuf[s] = *(const float4*)(kp + (size_t)nxt*Nn);
      mbuf[s] = *(const float4*)(mp + (size_t)nxt*Nn);
      float tm = m4.x*v[0] + m4.y*v[1] + m4.z*v[2] + m4.w*v[3];
      const float* wrow = &sW[ii + s];
      #pragma unroll
      for (int p = 0; p < 16; p++) {
        float wv = wrow[p*CHUNK];
        acc[p].x = fmaf(wv, k4.x, acc[p].x);
        acc[p].y = fmaf(wv, k4.y, acc[p].y);
        acc[p].z = fmaf(wv, k4.z, acc[p].z);
        acc[p].w = fmaf(wv, k4.w, acc[p].w);
        sa[p] = fmaf(wv, tm, sa[p]);
      }
    }
  }
  int lane = tid & 63;
  #pragma unroll
  for (int q = 0; q < Pp; q++) {
    float w0 = Wp[(size_t)(j0 + 0)*PPAD + q];
    float w1 = Wp[(size_t)(j0 + 1)*PPAD + q];
    float w2 = Wp[(size_t)(j0 + 2)*PPAD + q];
    float w3 = Wp[(size_t)(j0 + 3)*PPAD + q];
    float pr[16];
    #pragma unroll
    for (int p = 0; p < 16; p++)
      pr[p] = acc[p].x*w0 + acc[p].y*w1 + acc[p].z*w2 + acc[p].w*w3;
    #pragma unroll
    for (int p = 0; p < 16; p++) {
      float vq = pr[p];
      #pragma unroll
      for (int off = 32; off > 0; off >>= 1) vq += __shfl_xor(vq, off, 64);
      pr[p] = vq;
    }
    if (lane == 0) {
      #pragma unroll
      for (int p = 0; p < 16; p++)
        atomicAdd(&khat[(bf*16 + p)*Pp + q], pr[p] * INV_SCALE);
    }
  }
  #pragma unroll
  for (int p = 0; p < 16; p++) {
    float vq = sa[p];
    #pragma unroll
    for (int off = 32; off > 0; off >>= 1) vq += __shfl_xor(vq, off, 64);
    sa[p] = vq;
  }
  if (lane == 0) {
    #pragma unroll
    for (int p = 0; p < 16; p++) atomicAdd(&srca[bf*16 + p], sa[p] * INV_SCALE);
  }
}

// ---------------- damped fixed-point solver v2: 2 barriers/iter, no phase-0, packed LDS ----------------
// 384 threads (6 waves), 2 lanes per edge (h = tid&1 owns d-range of 32).
// A/B recomputed in-register (6 fma per d) -> sA/sB + its barrier + 1.14M bank conflicts deleted.
// W1 rows packed [d][8] = {2*W1[0..5,d], 2*bz[d], 0}; W2 packed [d][4]. All inner LDS reads are
// b128 with 2 distinct addresses/wave on identical banks (free 2-way broadcast).
__global__ __launch_bounds__(384, 1) void k_solve(
    const float* __restrict__ khat, const float* __restrict__ srca,
    const float* __restrict__ zacc, const float* __restrict__ Wz,
    const float* __restrict__ u_init, const float* __restrict__ Wf1,
    const float* __restrict__ bfv, const float* __restrict__ Wf2,
    float* __restrict__ ubuf) {
  int b = blockIdx.x;
  __shared__ float u4[Pp*4];           // u padded to float4 rows
  __shared__ float flux_s[Ee*Fc];
  __shared__ float sW1p[DZ*8];         // [d][8] = {2*W1[0..5,d], 2*bz[d], 0}
  __shared__ float sW2p[DZ*4];         // [d][4] = {W2[d,0..2], 0}
  __shared__ float sK[Fc*16*Pp];
  __shared__ float ssrc[Fc*16];
  int tid = threadIdx.x;
  for (int t = tid; t < 6*DZ; t += 384) {
    int k = t >> 6, d = t & 63;
    sW1p[d*8 + k] = 2.f * Wf1[t];
  }
  for (int t = tid; t < DZ*Fc; t += 384) {
    int d = t / 3, c = t - d*3;
    sW2p[d*4 + c] = Wf2[t];
  }
  if (tid < DZ) {
    float s = 0.f;
    for (int k = 0; k < DZ; k++) s = fmaf(zacc[b*DZ + k], Wz[k*DZ + tid], s);
    sW1p[tid*8 + 6] = 2.f * (bfv[tid] + s * (1.f/1024.f));   // 2*bz[d]
    sW1p[tid*8 + 7] = 0.f;
    sW2p[tid*4 + 3] = 0.f;
  }
  for (int t = tid; t < Fc*16*Pp; t += 384) sK[t] = khat[b*Fc*16*Pp + t];
  if (tid < 48) ssrc[tid] = srca[b*48 + tid];
  if (tid < 57) u4[(tid/3)*4 + (tid%3)] = u_init[b*57 + tid];
  if (tid < Pp) u4[tid*4 + 3] = 0.f;
  __syncthreads();
  int e = tid >> 1, h = tid & 1;
  bool active = (e < Ee);              // tid < 342
  int ei = 0, ej = 0;
  if (active) {
    int r = e, i = 0;
    while (r >= 18 - i) { r -= 18 - i; i++; }
    ei = i; ej = i + 1 + r;
  }
  int d0 = h * 32;
  bool upd = (tid < 57);
  int up = tid / 3, uf = tid - (tid/3)*3;
  for (int it = 0; it < ITERS; it++) {
    if (active) {
      float4 ua = *(const float4*)&u4[ei*4];
      float4 ub = *(const float4*)&u4[ej*4];
      float fl0 = 0.f, fl1 = 0.f, fl2 = 0.f;
      #pragma unroll 16
      for (int dd = 0; dd < 32; dd++) {
        int d = d0 + dd;
        float4 wA = *(const float4*)&sW1p[d*8];
        float4 wB = *(const float4*)&sW1p[d*8 + 4];
        float pre = wB.z;                          // 2*bz[d]
        pre = fmaf(ua.x, wA.x, pre);
        pre = fmaf(ua.y, wA.y, pre);
        pre = fmaf(ua.z, wA.z, pre);
        pre = fmaf(ub.x, wA.w, pre);
        pre = fmaf(ub.y, wB.x, pre);
        pre = fmaf(ub.z, wB.y, pre);
        float t = __expf(pre);                     // = exp(2x); saturates safely
        float r = __builtin_amdgcn_rcpf(t + 1.f);
        float th = fmaf(-2.f, r, 1.f);             // tanh(x) = 1 - 2/(e^2x+1)
        float4 w2 = *(const float4*)&sW2p[d*4];
        fl0 = fmaf(th, w2.x, fl0);
        fl1 = fmaf(th, w2.y, fl1);
        fl2 = fmaf(th, w2.z, fl2);
      }
      fl0 += __shfl_xor(fl0, 1, 64);
      fl1 += __shfl_xor(fl1, 1, 64);
      fl2 += __shfl_xor(fl2, 1, 64);
      if (h == 0) { flux_s[e*3+0] = fl0; flux_s[e*3+1] = fl1; flux_s[e*3+2] = fl2; }
    }
    __syncthreads();
    if (upd) {
      float u_old = u4[up*4 + uf];
      float r_;
      if (up < 16) {
        float diff = 0.f;
        const float* kr = &sK[(uf*16 + up)*Pp];
        for (int q = 0; q < Pp; q++) diff = fmaf(kr[q], u4[q*4 + uf], diff);
        float ft = 0.f;
        for (int o = 0; o < Pp; o++) {
          if (o == up) continue;
          int i_ = (o < up) ? o : up;
          int j_ = (o < up) ? up : o;
          int eidx = i_*Pp - (i_*(i_+1))/2 + (j_ - i_ - 1);
          float sgn = (o < up) ? 1.f : -1.f;
          ft += sgn * flux_s[eidx*3 + uf];
        }
        r_ = diff - ssrc[uf*16 + up] - ft;
      } else {
        r_ = u_old - ((up == 16) ? 1.f : 0.f);
      }
      u4[up*4 + uf] = u_old - 0.1f * r_;
    }
    __syncthreads();
  }
  if (tid < 57) ubuf[b*57 + tid] = u4[(tid/3)*4 + (tid%3)];
}

// ---------------- u_fine = einsum('bpif,bpf->bif') ----------------
__global__ __launch_bounds__(256) void k_out(const float* __restrict__ wproj,
                                             const float* __restrict__ ubuf,
                                             float* __restrict__ out) {
  __shared__ float u_s[57];
  int b = blockIdx.y;
  int i = blockIdx.x*256 + threadIdx.x;
  if (threadIdx.x < 57) u_s[threadIdx.x] = ubuf[b*57 + threadIdx.x];
  __syncthreads();
  #pragma unroll
  for (int f = 0; f < Fc; f++) {
    const float* row = wproj + ((size_t)(b*Fc + f)*Nn + i)*PPAD;
    float s = 0.f;
    #pragma unroll
    for (int p = 0; p < Pp; p++) s = fmaf(row[p], u_s[p*3 + f], s);
    out[((size_t)b*Nn + i)*Fc + f] = s;
  }
}

extern "C" void kernel_launch(void* const* d_in, const int* in_sizes, int n_in,
                              void* d_out, int out_size, void* d_ws, size_t ws_size,
                              hipStream_t stream) {
  const float* in_tokens = (const float*)d_in[0];
  const float* K_list    = (const float*)d_in[1];
  const float* M_list    = (const float*)d_in[2];
  const int*   dnodes    = (const int*)d_in[3];
  const float* bvals     = (const float*)d_in[4];
  const float* u_init    = (const float*)d_in[5];
  const float* W_enc     = (const float*)d_in[6];
  const float* b_enc     = (const float*)d_in[7];
  const float* W_src     = (const float*)d_in[8];
  const float* b_src     = (const float*)d_in[9];
  const float* W_pou     = (const float*)d_in[10];
  const float* Wf1       = (const float*)d_in[11];
  const float* Wz        = (const float*)d_in[12];
  const float* bfv       = (const float*)d_in[13];
  const float* Wf2       = (const float*)d_in[14];
  float* ws  = (float*)d_ws;
  float* out = (float*)d_out;

  float* WPROJ = ws + OFF_WPROJ;
  float* FFULL = ws + OFF_FFULL;
  float* FLAT  = ws + OFF_FLAT;
  float* UBUF  = ws + OFF_UBUF;
  float* BVALS = ws + OFF_BVALS;
  float* ZACC  = ws + OFF_ZACC;
  float* KHAT  = ws + OFF_KHAT;
  float* SRC   = ws + OFF_SRC;
  float* TPART = ws + OFF_TPART;

  hipMemsetAsync(ws + OFF_BVALS, 0, (size_t)ZERO_FLOATS * sizeof(float), stream);
  k_scatter<<<1, 1024, 0, stream>>>(dnodes, bvals, BVALS);
  k_encode<<<128, 128, 0, stream>>>(in_tokens, W_enc, b_enc, W_src, b_src, W_pou,
                                    BVALS, WPROJ, FFULL, ZACC);
  k_flat<<<Bn*Fc, 256, 0, stream>>>(WPROJ, FFULL, FLAT);
  if (ws_size >= (size_t)NEED_FLOATS * sizeof(float)) {
    k_projT<<<dim3(Nn/CHUNK, Bn*Fc), 256, 0, stream>>>(K_list, WPROJ, TPART);
    k_projM<<<dim3(Nn/CHUNK, Bn*Fc), 256, 0, stream>>>(M_list, WPROJ, FLAT, SRC);
    k_khat<<<dim3(16, Bn*Fc), 256, 0, stream>>>(TPART, WPROJ, KHAT);
  } else {
    k_project_fb<<<dim3(Nn/CHUNK, Bn*Fc), 256, 0, stream>>>(K_list, M_list, WPROJ, FLAT, KHAT, SRC);
  }
  k_solve<<<Bn, 384, 0, stream>>>(KHAT, SRC, ZACC, Wz, u_init, Wf1, bfv, Wf2, UBUF);
  k_out<<<dim3(Nn/256, Bn), 256, 0, stream>>>(WPROJ, UBUF, out);
}

// Round 5
// 733.925 us; speedup vs baseline: 1.0733x; 1.0733x over previous
//
#include <hip/hip_runtime.h>

#define Bn 16
#define Nn 1024
#define DIN 32
#define DZ 64
#define Fc 3
#define Pp 19
#define PPAD 20
#define Ee 171
#define ITERS 50
#define INV_SCALE (19.0f/1024.0f)
#define CHUNK 64
#define PF 4
#define PFK 8

// workspace offsets (in floats)
#define OFF_WPROJ 0         // [B][F][N][PPAD]  983040
#define OFF_FFULL 983040    // [B][N][F]        49152
#define OFF_FLAT  1033216   // [B][F][19]       912
#define OFF_UBUF  1034128   // [B][57]          912
#define OFF_BVALS 1035040   // [B][N][F]        49152   -- zero region start
#define OFF_ZACC  1084192   // [B][64]          1024
#define OFF_KHAT  1085216   // [B][F][16][19]   14592
#define OFF_SRC   1099808   // [B][F][16]       768
#define ZERO_FLOATS 65536   // BVALS+ZACC+KHAT+SRC contiguous
#define OFF_TPART 1100576   // [B*F][16 chunks][16 p][1024 j]  12582912 floats (48 MB)
#define NEED_FLOATS (OFF_TPART + 48*16*16*1024)

// ---------------- scatter boundary_vals (parallel, deterministic last-wins) ----------------
__global__ __launch_bounds__(1024) void k_scatter(const int* __restrict__ nodes,
                                                  const float* __restrict__ bvals,
                                                  float* __restrict__ bfull) {
  __shared__ int sn[1024];
  int tid = threadIdx.x;
  sn[tid] = nodes[tid];
  __syncthreads();
  int b = tid >> 6, j = tid & 63;
  int node = sn[tid];
  bool win = true;
  for (int j2 = j + 1; j2 < 64; j2++)
    if (sn[(b << 6) | j2] == node) { win = false; break; }
  if (win) {
    #pragma unroll
    for (int f = 0; f < Fc; f++)
      bfull[((size_t)b*Nn + node)*Fc + f] = bvals[(size_t)tid*Fc + f];
  }
}

// ---------------- encoder + POU softmax + f_full + zacc partials ----------------
__global__ __launch_bounds__(128) void k_encode(
    const float* __restrict__ x, const float* __restrict__ Wenc, const float* __restrict__ benc,
    const float* __restrict__ Wsrc, const float* __restrict__ bsrc, const float* __restrict__ Wpou,
    const float* __restrict__ bfull, float* __restrict__ wproj, float* __restrict__ ffull,
    float* __restrict__ zacc) {
  __shared__ float sWenc[DIN*DZ];
  __shared__ float sWpou[DZ*57];
  __shared__ float sWsrc[DZ*Fc];
  int tid = threadIdx.x;
  for (int t = tid; t < DIN*DZ; t += 128) sWenc[t] = Wenc[t];
  for (int t = tid; t < DZ*57; t += 128) sWpou[t] = Wpou[t];
  for (int t = tid; t < DZ*Fc; t += 128) sWsrc[t] = Wsrc[t];
  __syncthreads();
  int g = blockIdx.x*128 + tid;         // b*N + i
  int b = g >> 10, i = g & 1023;
  float xr[DIN];
  const float* xp = x + (size_t)g*DIN;
  #pragma unroll
  for (int k = 0; k < DIN; k += 4) {
    float4 t4 = *(const float4*)(xp + k);
    xr[k] = t4.x; xr[k+1] = t4.y; xr[k+2] = t4.z; xr[k+3] = t4.w;
  }
  float l[57];
  #pragma unroll
  for (int o = 0; o < 57; o++) l[o] = 0.f;
  float ff[3] = {bsrc[0], bsrc[1], bsrc[2]};
  int lane = tid & 63;
  for (int d = 0; d < DZ; d++) {
    float zd = benc[d];
    #pragma unroll
    for (int k = 0; k < DIN; k++) zd = fmaf(xr[k], sWenc[k*DZ + d], zd);
    zd = tanhf(zd);
    #pragma unroll
    for (int o = 0; o < 57; o++) l[o] = fmaf(zd, sWpou[d*57 + o], l[o]);
    #pragma unroll
    for (int f = 0; f < Fc; f++) ff[f] = fmaf(zd, sWsrc[d*Fc + f], ff[f]);
    float zs = zd;
    #pragma unroll
    for (int off = 32; off > 0; off >>= 1) zs += __shfl_xor(zs, off, 64);
    if (lane == 0) atomicAdd(&zacc[b*DZ + d], zs);
  }
  #pragma unroll
  for (int f = 0; f < Fc; f++) ffull[(size_t)g*Fc + f] = ff[f];
  #pragma unroll
  for (int f = 0; f < Fc; f++) {
    float bv = bfull[(size_t)g*Fc + f];
    l[16*3+f] += bv; l[17*3+f] += bv; l[18*3+f] += bv;
  }
  #pragma unroll
  for (int f = 0; f < Fc; f++) {
    float m = l[f];
    #pragma unroll
    for (int p = 1; p < Pp; p++) m = fmaxf(m, l[p*3+f]);
    float ex[Pp]; float s = 0.f;
    #pragma unroll
    for (int p = 0; p < Pp; p++) { ex[p] = __expf(l[p*3+f] - m); s += ex[p]; }
    float inv = 1.f / s;
    float* wp = wproj + ((size_t)(b*Fc + f)*Nn + i)*PPAD;
    #pragma unroll
    for (int p = 0; p < Pp; p++) wp[p] = ex[p]*inv;
  }
}

// ---------------- f_latent[b,f,q] = (1/scale) sum_i W[q,i] f_full[i,f] ----------------
__global__ __launch_bounds__(256) void k_flat(const float* __restrict__ wproj,
                                              const float* __restrict__ ffull,
                                              float* __restrict__ flat) {
  int bf = blockIdx.x;                 // b*3+f
  int b = bf / 3, f = bf % 3;
  float acc[Pp];
  #pragma unroll
  for (int q = 0; q < Pp; q++) acc[q] = 0.f;
  for (int i = threadIdx.x; i < Nn; i += 256) {
    float fv = ffull[((size_t)b*Nn + i)*Fc + f];
    const float* row = wproj + ((size_t)bf*Nn + i)*PPAD;
    #pragma unroll
    for (int q = 0; q < Pp; q++) acc[q] = fmaf(row[q], fv, acc[q]);
  }
  #pragma unroll
  for (int q = 0; q < Pp; q++) {
    float v = acc[q];
    #pragma unroll
    for (int off = 32; off > 0; off >>= 1) v += __shfl_xor(v, off, 64);
    acc[q] = v;
  }
  __shared__ float red[4][Pp];
  int wave = threadIdx.x >> 6, lane = threadIdx.x & 63;
  if (lane == 0) {
    #pragma unroll
    for (int q = 0; q < Pp; q++) red[wave][q] = acc[q];
  }
  __syncthreads();
  if (threadIdx.x < Pp) {
    float s = red[0][threadIdx.x] + red[1][threadIdx.x] + red[2][threadIdx.x] + red[3][threadIdx.x];
    flat[bf*Pp + threadIdx.x] = s * INV_SCALE;
  }
}

// ---------------- K pass: T_chunk[p, j] = sum_i W[p,i] K[i,j]  (coalesced float4 out) ----------------
__global__ __launch_bounds__(256, 3) void k_projT(
    const float* __restrict__ Kl, const float* __restrict__ wproj,
    float* __restrict__ tpart) {
  __shared__ float sW[16*CHUNK];       // sW[p*64 + r] = W[p, i0+r]
  int chunk = blockIdx.x;              // 16 i-chunks of 64
  int bf = blockIdx.y;                 // 48
  int i0 = chunk * CHUNK;
  const float* Kb = Kl + (size_t)bf*Nn*Nn + (size_t)i0*Nn;
  const float* Wrow0 = wproj + ((size_t)bf*Nn + i0)*PPAD;
  int tid = threadIdx.x;
  for (int t = tid; t < 16*CHUNK; t += 256) {
    int r = t & (CHUNK-1), p = t >> 6;
    sW[p*CHUNK + r] = Wrow0[r*PPAD + p];
  }
  __syncthreads();
  int j0 = tid * 4;
  float4 acc[16];
  #pragma unroll
  for (int p = 0; p < 16; p++) { acc[p].x = 0.f; acc[p].y = 0.f; acc[p].z = 0.f; acc[p].w = 0.f; }
  const float* kp = Kb + j0;
  float4 kbuf[PFK];
  #pragma unroll
  for (int s = 0; s < PFK; s++) kbuf[s] = *(const float4*)(kp + (size_t)s*Nn);
  for (int ii = 0; ii < CHUNK; ii += PFK) {
    #pragma unroll
    for (int s = 0; s < PFK; s++) {
      float4 k4 = kbuf[s];
      int nxt = (ii + PFK + s) & (CHUNK - 1);   // tail wraps to rows 0..7 (L2-hot, harmless)
      kbuf[s] = *(const float4*)(kp + (size_t)nxt*Nn);
      const float* wrow = &sW[ii + s];           // wave-uniform -> LDS broadcast
      #pragma unroll
      for (int p = 0; p < 16; p++) {
        float wv = wrow[p*CHUNK];
        acc[p].x = fmaf(wv, k4.x, acc[p].x);
        acc[p].y = fmaf(wv, k4.y, acc[p].y);
        acc[p].z = fmaf(wv, k4.z, acc[p].z);
        acc[p].w = fmaf(wv, k4.w, acc[p].w);
      }
    }
  }
  float* tp = tpart + ((size_t)(bf*16 + chunk)*16)*Nn + j0;
  #pragma unroll
  for (int p = 0; p < 16; p++) *(float4*)(tp + (size_t)p*Nn) = acc[p];
}

// ---------------- M pass: src[p] = (1/s) sum_i W[p,i] (M[i,:].Wv)  ----------------
__global__ __launch_bounds__(256, 3) void k_projM(
    const float* __restrict__ Ml, const float* __restrict__ wproj,
    const float* __restrict__ flat, float* __restrict__ srca) {
  __shared__ float sW[16*CHUNK];
  int chunk = blockIdx.x;
  int bf = blockIdx.y;
  int i0 = chunk * CHUNK;
  const float* Mb = Ml + (size_t)bf*Nn*Nn + (size_t)i0*Nn;
  const float* Wp = wproj + (size_t)bf*Nn*PPAD;
  const float* Wrow0 = Wp + (size_t)i0*PPAD;
  int tid = threadIdx.x;
  for (int t = tid; t < 16*CHUNK; t += 256) {
    int r = t & (CHUNK-1), p = t >> 6;
    sW[p*CHUNK + r] = Wrow0[r*PPAD + p];
  }
  // v[r] = sum_q W[q, j0+r] * fl[q]
  float fl[Pp];
  #pragma unroll
  for (int q = 0; q < Pp; q++) fl[q] = flat[bf*Pp + q];
  int j0 = tid * 4;
  float v0, v1, v2, v3;
  {
    float vv[4];
    #pragma unroll
    for (int r = 0; r < 4; r++) {
      const float* row = Wp + (size_t)(j0 + r)*PPAD;
      float s = 0.f;
      #pragma unroll
      for (int q = 0; q < Pp; q++) s = fmaf(row[q], fl[q], s);
      vv[r] = s;
    }
    v0 = vv[0]; v1 = vv[1]; v2 = vv[2]; v3 = vv[3];
  }
  __syncthreads();
  float sa[16];
  #pragma unroll
  for (int p = 0; p < 16; p++) sa[p] = 0.f;
  const float* mp = Mb + j0;
  float4 mbuf[PFK];
  #pragma unroll
  for (int s = 0; s < PFK; s++) mbuf[s] = *(const float4*)(mp + (size_t)s*Nn);
  for (int ii = 0; ii < CHUNK; ii += PFK) {
    #pragma unroll
    for (int s = 0; s < PFK; s++) {
      float4 m4 = mbuf[s];
      int nxt = (ii + PFK + s) & (CHUNK - 1);
      mbuf[s] = *(const float4*)(mp + (size_t)nxt*Nn);
      float tm = m4.x*v0 + m4.y*v1 + m4.z*v2 + m4.w*v3;
      const float* wrow = &sW[ii + s];
      #pragma unroll
      for (int p = 0; p < 16; p++) sa[p] = fmaf(wrow[p*CHUNK], tm, sa[p]);
    }
  }
  int lane = tid & 63;
  #pragma unroll
  for (int p = 0; p < 16; p++) {
    float vq = sa[p];
    #pragma unroll
    for (int off = 32; off > 0; off >>= 1) vq += __shfl_xor(vq, off, 64);
    sa[p] = vq;
  }
  if (lane == 0) {
    #pragma unroll
    for (int p = 0; p < 16; p++) atomicAdd(&srca[bf*16 + p], sa[p] * INV_SCALE);
  }
}

// ---------------- khat[p][q] = INV_SCALE * sum_j (sum_c Tpart[c][p][j]) * W[q][j] ----------------
__global__ __launch_bounds__(256) void k_khat(const float* __restrict__ tpart,
                                              const float* __restrict__ wproj,
                                              float* __restrict__ khat) {
  __shared__ float sT[16*64];          // [p][r]
  __shared__ float sWq[64*PPAD];       // [r][q]
  int jb = blockIdx.x, bf = blockIdx.y;
  int tid = threadIdx.x;
  {
    int id = tid * 4;                  // 4 consecutive floats of one p-row
    int p = id >> 6;
    int r = id & 63;
    const float* base = tpart + ((size_t)(bf*16)*16 + p)*Nn + jb*64 + r;
    float4 s4 = make_float4(0.f, 0.f, 0.f, 0.f);
    #pragma unroll 4
    for (int c = 0; c < 16; c++) {
      float4 t4 = *(const float4*)(base + (size_t)c*16*Nn);
      s4.x += t4.x; s4.y += t4.y; s4.z += t4.z; s4.w += t4.w;
    }
    *(float4*)&sT[p*64 + r] = s4;
  }
  const float* wsrc = wproj + ((size_t)bf*Nn + jb*64)*PPAD;   // 1280 contiguous floats
  for (int t = tid; t < 64*PPAD; t += 256) sWq[t] = wsrc[t];
  __syncthreads();
  for (int o = tid; o < 16*Pp; o += 256) {
    int p = o / Pp, q = o - p*Pp;
    float s = 0.f;
    #pragma unroll
    for (int r = 0; r < 64; r++) s = fmaf(sT[p*64 + r], sWq[r*PPAD + q], s);
    atomicAdd(&khat[(bf*16 + p)*Pp + q], s * INV_SCALE);
  }
}

// ---------------- fallback heavy pass (round-1 version) if workspace too small ----------------
__global__ __launch_bounds__(256, 1) void k_project_fb(
    const float* __restrict__ Kl, const float* __restrict__ Ml,
    const float* __restrict__ wproj, const float* __restrict__ flat,
    float* __restrict__ khat, float* __restrict__ srca) {
  __shared__ float sW[16*CHUNK];
  int chunk = blockIdx.x;
  int bf = blockIdx.y;
  int i0 = chunk * CHUNK;
  const float* Kb = Kl + (size_t)bf*Nn*Nn + (size_t)i0*Nn;
  const float* Mb = Ml + (size_t)bf*Nn*Nn + (size_t)i0*Nn;
  const float* Wp = wproj + (size_t)bf*Nn*PPAD;
  const float* Wrow0 = Wp + (size_t)i0*PPAD;
  int tid = threadIdx.x;
  for (int t = tid; t < 16*CHUNK; t += 256) {
    int r = t & (CHUNK-1), p = t >> 6;
    sW[p*CHUNK + r] = Wrow0[r*PPAD + p];
  }
  float fl[Pp];
  #pragma unroll
  for (int q = 0; q < Pp; q++) fl[q] = flat[bf*Pp + q];
  int j0 = tid * 4;
  float v[4];
  #pragma unroll
  for (int r = 0; r < 4; r++) {
    const float* row = Wp + (size_t)(j0 + r)*PPAD;
    float s = 0.f;
    #pragma unroll
    for (int q = 0; q < Pp; q++) s = fmaf(row[q], fl[q], s);
    v[r] = s;
  }
  __syncthreads();
  float4 acc[16];
  float sa[16];
  #pragma unroll
  for (int p = 0; p < 16; p++) {
    acc[p].x = 0.f; acc[p].y = 0.f; acc[p].z = 0.f; acc[p].w = 0.f;
    sa[p] = 0.f;
  }
  const float* kp = Kb + j0;
  const float* mp = Mb + j0;
  float4 kbuf[PF], mbuf[PF];
  #pragma unroll
  for (int s = 0; s < PF; s++) {
    kbuf[s] = *(const float4*)(kp + (size_t)s*Nn);
    mbuf[s] = *(const float4*)(mp + (size_t)s*Nn);
  }
  for (int ii = 0; ii < CHUNK; ii += PF) {
    #pragma unroll
    for (int s = 0; s < PF; s++) {
      float4 k4 = kbuf[s], m4 = mbuf[s];
      int nxt = (ii + PF + s) & (CHUNK - 1);
      kbuf[s] = *(const float4*)(kp + (size_t)nxt*Nn);
      mbuf[s] = *(const float4*)(mp + (size_t)nxt*Nn);
      float tm = m4.x*v[0] + m4.y*v[1] + m4.z*v[2] + m4.w*v[3];
      const float* wrow = &sW[ii + s];
      #pragma unroll
      for (int p = 0; p < 16; p++) {
        float wv = wrow[p*CHUNK];
        acc[p].x = fmaf(wv, k4.x, acc[p].x);
        acc[p].y = fmaf(wv, k4.y, acc[p].y);
        acc[p].z = fmaf(wv, k4.z, acc[p].z);
        acc[p].w = fmaf(wv, k4.w, acc[p].w);
        sa[p] = fmaf(wv, tm, sa[p]);
      }
    }
  }
  int lane = tid & 63;
  #pragma unroll
  for (int q = 0; q < Pp; q++) {
    float w0 = Wp[(size_t)(j0 + 0)*PPAD + q];
    float w1 = Wp[(size_t)(j0 + 1)*PPAD + q];
    float w2 = Wp[(size_t)(j0 + 2)*PPAD + q];
    float w3 = Wp[(size_t)(j0 + 3)*PPAD + q];
    float pr[16];
    #pragma unroll
    for (int p = 0; p < 16; p++)
      pr[p] = acc[p].x*w0 + acc[p].y*w1 + acc[p].z*w2 + acc[p].w*w3;
    #pragma unroll
    for (int p = 0; p < 16; p++) {
      float vq = pr[p];
      #pragma unroll
      for (int off = 32; off > 0; off >>= 1) vq += __shfl_xor(vq, off, 64);
      pr[p] = vq;
    }
    if (lane == 0) {
      #pragma unroll
      for (int p = 0; p < 16; p++)
        atomicAdd(&khat[(bf*16 + p)*Pp + q], pr[p] * INV_SCALE);
    }
  }
  #pragma unroll
  for (int p = 0; p < 16; p++) {
    float vq = sa[p];
    #pragma unroll
    for (int off = 32; off > 0; off >>= 1) vq += __shfl_xor(vq, off, 64);
    sa[p] = vq;
  }
  if (lane == 0) {
    #pragma unroll
    for (int p = 0; p < 16; p++) atomicAdd(&srca[bf*16 + p], sa[p] * INV_SCALE);
  }
}

// ---------------- damped fixed-point solver v3: weights in registers, d-split across lanes ----
// 256 threads (4 waves). Lane = g*8+sub: g = edge slot (8/wave), sub owns d = sub*8..sub*8+7.
// Per-lane regs: 2*W1 (48) + 2*bz (8) + W2 (24) = 80 -- loaded ONCE, zero LDS traffic in the
// hot loop except two broadcast b128 u-reads per edge. 6 rounds x 32 edge slots covers 171 edges.
// tanh(x) = 1 - 2*rcp(exp(2x)+1); the *2 is folded into the stored weights.
__global__ __launch_bounds__(256, 1) void k_solve(
    const float* __restrict__ khat, const float* __restrict__ srca,
    const float* __restrict__ zacc, const float* __restrict__ Wz,
    const float* __restrict__ u_init, const float* __restrict__ Wf1,
    const float* __restrict__ bfv, const float* __restrict__ Wf2,
    float* __restrict__ ubuf) {
  int b = blockIdx.x;
  __shared__ float u4[Pp*4];           // u padded to float4 rows
  __shared__ float flux_s[Ee*Fc];
  __shared__ float sbz[DZ];
  __shared__ float sK[Fc*16*Pp];
  __shared__ float ssrc[Fc*16];
  int tid = threadIdx.x;
  if (tid < DZ) {
    float s = 0.f;
    for (int k = 0; k < DZ; k++) s = fmaf(zacc[b*DZ + k], Wz[k*DZ + tid], s);
    sbz[tid] = bfv[tid] + s * (1.f/1024.f);
  }
  for (int t = tid; t < Fc*16*Pp; t += 256) sK[t] = khat[b*Fc*16*Pp + t];
  if (tid < 48) ssrc[tid] = srca[b*48 + tid];
  if (tid < 57) u4[(tid/3)*4 + (tid%3)] = u_init[b*57 + tid];
  if (tid < Pp) u4[tid*4 + 3] = 0.f;
  __syncthreads();

  int wave = tid >> 6, lane = tid & 63;
  int g = lane >> 3, sub = lane & 7;
  int dbase = sub * 8;
  // ---- loop-invariant weights into registers (x2 pre-folded for the exp(2x) form) ----
  float w1r[6][8];
  #pragma unroll
  for (int k = 0; k < 6; k++)
    #pragma unroll
    for (int j = 0; j < 8; j++) w1r[k][j] = 2.f * Wf1[k*DZ + dbase + j];
  float bzr[8];
  #pragma unroll
  for (int j = 0; j < 8; j++) bzr[j] = 2.f * sbz[dbase + j];
  float w2r[3][8];
  #pragma unroll
  for (int j = 0; j < 8; j++) {
    w2r[0][j] = Wf2[(dbase + j)*3 + 0];
    w2r[1][j] = Wf2[(dbase + j)*3 + 1];
    w2r[2][j] = Wf2[(dbase + j)*3 + 2];
  }
  // ---- per-round edge decode (6 rounds x 32 slots >= 171 edges), done once ----
  int e_[6], ei_[6], ej_[6];
  bool act_[6];
  #pragma unroll
  for (int rd = 0; rd < 6; rd++) {
    int e = rd*32 + wave*8 + g;
    act_[rd] = (e < Ee);
    int r = act_[rd] ? e : 0, i = 0;
    while (r >= 18 - i) { r -= 18 - i; i++; }
    e_[rd] = e; ei_[rd] = i; ej_[rd] = i + 1 + r;
  }
  bool upd = (tid < 57);
  int up = tid / 3, uf = tid - (tid/3)*3;

  for (int it = 0; it < ITERS; it++) {
    // ---- flux phase: pure-register math, 2 broadcast LDS reads per edge ----
    #pragma unroll
    for (int rd = 0; rd < 6; rd++) {
      if (act_[rd]) {
        float4 ua = *(const float4*)&u4[ei_[rd]*4];
        float4 ub = *(const float4*)&u4[ej_[rd]*4];
        float fl0 = 0.f, fl1 = 0.f, fl2 = 0.f;
        #pragma unroll
        for (int j = 0; j < 8; j++) {
          float pre = bzr[j];                       // = 2x
          pre = fmaf(ua.x, w1r[0][j], pre);
          pre = fmaf(ua.y, w1r[1][j], pre);
          pre = fmaf(ua.z, w1r[2][j], pre);
          pre = fmaf(ub.x, w1r[3][j], pre);
          pre = fmaf(ub.y, w1r[4][j], pre);
          pre = fmaf(ub.z, w1r[5][j], pre);
          float t = __expf(pre);                    // exp(2x), saturates safely
          float rr = __builtin_amdgcn_rcpf(t + 1.f);
          float th = fmaf(-2.f, rr, 1.f);           // tanh(x)
          fl0 = fmaf(th, w2r[0][j], fl0);
          fl1 = fmaf(th, w2r[1][j], fl1);
          fl2 = fmaf(th, w2r[2][j], fl2);
        }
        fl0 += __shfl_xor(fl0, 1, 64); fl0 += __shfl_xor(fl0, 2, 64); fl0 += __shfl_xor(fl0, 4, 64);
        fl1 += __shfl_xor(fl1, 1, 64); fl1 += __shfl_xor(fl1, 2, 64); fl1 += __shfl_xor(fl1, 4, 64);
        fl2 += __shfl_xor(fl2, 1, 64); fl2 += __shfl_xor(fl2, 2, 64); fl2 += __shfl_xor(fl2, 4, 64);
        if (sub == 0) {
          flux_s[e_[rd]*3 + 0] = fl0;
          flux_s[e_[rd]*3 + 1] = fl1;
          flux_s[e_[rd]*3 + 2] = fl2;
        }
      }
    }
    __syncthreads();
    // ---- update phase (one value per lane, 57 lanes) ----
    if (upd) {
      float u_old = u4[up*4 + uf];
      float r_;
      if (up < 16) {
        float diff = 0.f;
        const float* kr = &sK[(uf*16 + up)*Pp];
        #pragma unroll
        for (int q = 0; q < Pp; q++) diff = fmaf(kr[q], u4[q*4 + uf], diff);
        float ft = 0.f;
        #pragma unroll
        for (int o = 0; o < Pp; o++) {
          if (o == up) continue;
          int i_ = (o < up) ? o : up;
          int j_ = (o < up) ? up : o;
          int eidx = i_*Pp - (i_*(i_+1))/2 + (j_ - i_ - 1);
          float sgn = (o < up) ? 1.f : -1.f;
          ft += sgn * flux_s[eidx*3 + uf];
        }
        r_ = diff - ssrc[uf*16 + up] - ft;
      } else {
        r_ = u_old - ((up == 16) ? 1.f : 0.f);
      }
      u4[up*4 + uf] = u_old - 0.1f * r_;
    }
    __syncthreads();
  }
  if (tid < 57) ubuf[b*57 + tid] = u4[(tid/3)*4 + (tid%3)];
}

// ---------------- u_fine = einsum('bpif,bpf->bif') ----------------
__global__ __launch_bounds__(256) void k_out(const float* __restrict__ wproj,
                                             const float* __restrict__ ubuf,
                                             float* __restrict__ out) {
  __shared__ float u_s[57];
  int b = blockIdx.y;
  int i = blockIdx.x*256 + threadIdx.x;
  if (threadIdx.x < 57) u_s[threadIdx.x] = ubuf[b*57 + threadIdx.x];
  __syncthreads();
  #pragma unroll
  for (int f = 0; f < Fc; f++) {
    const float* row = wproj + ((size_t)(b*Fc + f)*Nn + i)*PPAD;
    float s = 0.f;
    #pragma unroll
    for (int p = 0; p < Pp; p++) s = fmaf(row[p], u_s[p*3 + f], s);
    out[((size_t)b*Nn + i)*Fc + f] = s;
  }
}

extern "C" void kernel_launch(void* const* d_in, const int* in_sizes, int n_in,
                              void* d_out, int out_size, void* d_ws, size_t ws_size,
                              hipStream_t stream) {
  const float* in_tokens = (const float*)d_in[0];
  const float* K_list    = (const float*)d_in[1];
  const float* M_list    = (const float*)d_in[2];
  const int*   dnodes    = (const int*)d_in[3];
  const float* bvals     = (const float*)d_in[4];
  const float* u_init    = (const float*)d_in[5];
  const float* W_enc     = (const float*)d_in[6];
  const float* b_enc     = (const float*)d_in[7];
  const float* W_src     = (const float*)d_in[8];
  const float* b_src     = (const float*)d_in[9];
  const float* W_pou     = (const float*)d_in[10];
  const float* Wf1       = (const float*)d_in[11];
  const float* Wz        = (const float*)d_in[12];
  const float* bfv       = (const float*)d_in[13];
  const float* Wf2       = (const float*)d_in[14];
  float* ws  = (float*)d_ws;
  float* out = (float*)d_out;

  float* WPROJ = ws + OFF_WPROJ;
  float* FFULL = ws + OFF_FFULL;
  float* FLAT  = ws + OFF_FLAT;
  float* UBUF  = ws + OFF_UBUF;
  float* BVALS = ws + OFF_BVALS;
  float* ZACC  = ws + OFF_ZACC;
  float* KHAT  = ws + OFF_KHAT;
  float* SRC   = ws + OFF_SRC;
  float* TPART = ws + OFF_TPART;

  hipMemsetAsync(ws + OFF_BVALS, 0, (size_t)ZERO_FLOATS * sizeof(float), stream);
  k_scatter<<<1, 1024, 0, stream>>>(dnodes, bvals, BVALS);
  k_encode<<<128, 128, 0, stream>>>(in_tokens, W_enc, b_enc, W_src, b_src, W_pou,
                                    BVALS, WPROJ, FFULL, ZACC);
  k_flat<<<Bn*Fc, 256, 0, stream>>>(WPROJ, FFULL, FLAT);
  if (ws_size >= (size_t)NEED_FLOATS * sizeof(float)) {
    k_projT<<<dim3(Nn/CHUNK, Bn*Fc), 256, 0, stream>>>(K_list, WPROJ, TPART);
    k_projM<<<dim3(Nn/CHUNK, Bn*Fc), 256, 0, stream>>>(M_list, WPROJ, FLAT, SRC);
    k_khat<<<dim3(16, Bn*Fc), 256, 0, stream>>>(TPART, WPROJ, KHAT);
  } else {
    k_project_fb<<<dim3(Nn/CHUNK, Bn*Fc), 256, 0, stream>>>(K_list, M_list, WPROJ, FLAT, KHAT, SRC);
  }
  k_solve<<<Bn, 256, 0, stream>>>(KHAT, SRC, ZACC, Wz, u_init, Wf1, bfv, Wf2, UBUF);
  k_out<<<dim3(Nn/256, Bn), 256, 0, stream>>>(WPROJ, UBUF, out);
}

// Round 6
// 733.637 us; speedup vs baseline: 1.0737x; 1.0004x over previous
//
#include <hip/hip_runtime.h>

#define Bn 16
#define Nn 1024
#define DIN 32
#define DZ 64
#define Fc 3
#define Pp 19
#define PPAD 20
#define Ee 171
#define ITERS 50
#define INV_SCALE (19.0f/1024.0f)
#define CHUNK 64
#define PF 4
#define PFK 8
#define WPACK_B 1024   // 64 d x 16 floats per batch

// workspace offsets (in floats)
#define OFF_WPROJ 0         // [B][F][N][PPAD]  983040
#define OFF_FFULL 983040    // [B][N][F]        49152
#define OFF_FLAT  1033216   // [B][F][19]       912
#define OFF_UBUF  1034128   // [B][57]          912
#define OFF_BVALS 1035040   // [B][N][F]        49152   -- zero region start
#define OFF_ZACC  1084192   // [B][64]          1024
#define OFF_KHAT  1085216   // [B][F][16][19]   14592
#define OFF_SRC   1099808   // [B][F][16]       768
#define ZERO_FLOATS 65536   // BVALS+ZACC+KHAT+SRC contiguous
#define OFF_WPACK 1100576   // [B][64][16]      16384
#define OFF_TPART 1116960   // [B*F][16 chunks][16 p][1024 j]  12582912 floats (48 MB)
#define NEED_FLOATS (OFF_TPART + 48*16*16*1024)

// ---------------- scatter boundary_vals (parallel, deterministic last-wins) ----------------
__global__ __launch_bounds__(1024) void k_scatter(const int* __restrict__ nodes,
                                                  const float* __restrict__ bvals,
                                                  float* __restrict__ bfull) {
  __shared__ int sn[1024];
  int tid = threadIdx.x;
  sn[tid] = nodes[tid];
  __syncthreads();
  int b = tid >> 6, j = tid & 63;
  int node = sn[tid];
  bool win = true;
  for (int j2 = j + 1; j2 < 64; j2++)
    if (sn[(b << 6) | j2] == node) { win = false; break; }
  if (win) {
    #pragma unroll
    for (int f = 0; f < Fc; f++)
      bfull[((size_t)b*Nn + node)*Fc + f] = bvals[(size_t)tid*Fc + f];
  }
}

// ---------------- encoder + POU softmax + f_full + zacc partials ----------------
__global__ __launch_bounds__(128) void k_encode(
    const float* __restrict__ x, const float* __restrict__ Wenc, const float* __restrict__ benc,
    const float* __restrict__ Wsrc, const float* __restrict__ bsrc, const float* __restrict__ Wpou,
    const float* __restrict__ bfull, float* __restrict__ wproj, float* __restrict__ ffull,
    float* __restrict__ zacc) {
  __shared__ float sWenc[DIN*DZ];
  __shared__ float sWpou[DZ*57];
  __shared__ float sWsrc[DZ*Fc];
  int tid = threadIdx.x;
  for (int t = tid; t < DIN*DZ; t += 128) sWenc[t] = Wenc[t];
  for (int t = tid; t < DZ*57; t += 128) sWpou[t] = Wpou[t];
  for (int t = tid; t < DZ*Fc; t += 128) sWsrc[t] = Wsrc[t];
  __syncthreads();
  int g = blockIdx.x*128 + tid;         // b*N + i
  int b = g >> 10, i = g & 1023;
  float xr[DIN];
  const float* xp = x + (size_t)g*DIN;
  #pragma unroll
  for (int k = 0; k < DIN; k += 4) {
    float4 t4 = *(const float4*)(xp + k);
    xr[k] = t4.x; xr[k+1] = t4.y; xr[k+2] = t4.z; xr[k+3] = t4.w;
  }
  float l[57];
  #pragma unroll
  for (int o = 0; o < 57; o++) l[o] = 0.f;
  float ff[3] = {bsrc[0], bsrc[1], bsrc[2]};
  int lane = tid & 63;
  for (int d = 0; d < DZ; d++) {
    float zd = benc[d];
    #pragma unroll
    for (int k = 0; k < DIN; k++) zd = fmaf(xr[k], sWenc[k*DZ + d], zd);
    zd = tanhf(zd);
    #pragma unroll
    for (int o = 0; o < 57; o++) l[o] = fmaf(zd, sWpou[d*57 + o], l[o]);
    #pragma unroll
    for (int f = 0; f < Fc; f++) ff[f] = fmaf(zd, sWsrc[d*Fc + f], ff[f]);
    float zs = zd;
    #pragma unroll
    for (int off = 32; off > 0; off >>= 1) zs += __shfl_xor(zs, off, 64);
    if (lane == 0) atomicAdd(&zacc[b*DZ + d], zs);
  }
  #pragma unroll
  for (int f = 0; f < Fc; f++) ffull[(size_t)g*Fc + f] = ff[f];
  #pragma unroll
  for (int f = 0; f < Fc; f++) {
    float bv = bfull[(size_t)g*Fc + f];
    l[16*3+f] += bv; l[17*3+f] += bv; l[18*3+f] += bv;
  }
  #pragma unroll
  for (int f = 0; f < Fc; f++) {
    float m = l[f];
    #pragma unroll
    for (int p = 1; p < Pp; p++) m = fmaxf(m, l[p*3+f]);
    float ex[Pp]; float s = 0.f;
    #pragma unroll
    for (int p = 0; p < Pp; p++) { ex[p] = __expf(l[p*3+f] - m); s += ex[p]; }
    float inv = 1.f / s;
    float* wp = wproj + ((size_t)(b*Fc + f)*Nn + i)*PPAD;
    #pragma unroll
    for (int p = 0; p < Pp; p++) wp[p] = ex[p]*inv;
  }
}

// ---------------- f_latent[b,f,q] = (1/scale) sum_i W[q,i] f_full[i,f] ----------------
__global__ __launch_bounds__(256) void k_flat(const float* __restrict__ wproj,
                                              const float* __restrict__ ffull,
                                              float* __restrict__ flat) {
  int bf = blockIdx.x;                 // b*3+f
  int b = bf / 3, f = bf % 3;
  float acc[Pp];
  #pragma unroll
  for (int q = 0; q < Pp; q++) acc[q] = 0.f;
  for (int i = threadIdx.x; i < Nn; i += 256) {
    float fv = ffull[((size_t)b*Nn + i)*Fc + f];
    const float* row = wproj + ((size_t)bf*Nn + i)*PPAD;
    #pragma unroll
    for (int q = 0; q < Pp; q++) acc[q] = fmaf(row[q], fv, acc[q]);
  }
  #pragma unroll
  for (int q = 0; q < Pp; q++) {
    float v = acc[q];
    #pragma unroll
    for (int off = 32; off > 0; off >>= 1) v += __shfl_xor(v, off, 64);
    acc[q] = v;
  }
  __shared__ float red[4][Pp];
  int wave = threadIdx.x >> 6, lane = threadIdx.x & 63;
  if (lane == 0) {
    #pragma unroll
    for (int q = 0; q < Pp; q++) red[wave][q] = acc[q];
  }
  __syncthreads();
  if (threadIdx.x < Pp) {
    float s = red[0][threadIdx.x] + red[1][threadIdx.x] + red[2][threadIdx.x] + red[3][threadIdx.x];
    flat[bf*Pp + threadIdx.x] = s * INV_SCALE;
  }
}

// ---------------- pack flux-MLP weights per (b, d): {2*W1[0..5,d], 2*bz, pad, W2[d,0..2], pad} ---
__global__ __launch_bounds__(64) void k_wpack(
    const float* __restrict__ zacc, const float* __restrict__ Wz,
    const float* __restrict__ bfv, const float* __restrict__ Wf1,
    const float* __restrict__ Wf2, float* __restrict__ wpack) {
  int b = blockIdx.x, d = threadIdx.x;
  float s = 0.f;
  for (int k = 0; k < DZ; k++) s = fmaf(zacc[b*DZ + k], Wz[k*DZ + d], s);
  float bz = bfv[d] + s * (1.f/1024.f);
  float* w = wpack + (size_t)b*WPACK_B + d*16;
  #pragma unroll
  for (int k = 0; k < 6; k++) w[k] = 2.f * Wf1[k*DZ + d];
  w[6] = 2.f * bz;
  w[7] = 0.f;
  w[8]  = Wf2[d*3 + 0];
  w[9]  = Wf2[d*3 + 1];
  w[10] = Wf2[d*3 + 2];
  w[11] = 0.f; w[12] = 0.f; w[13] = 0.f; w[14] = 0.f; w[15] = 0.f;
}

// ---------------- K pass: T_chunk[p, j] = sum_i W[p,i] K[i,j]  (coalesced float4 out) ----------------
__global__ __launch_bounds__(256, 3) void k_projT(
    const float* __restrict__ Kl, const float* __restrict__ wproj,
    float* __restrict__ tpart) {
  __shared__ float sW[16*CHUNK];       // sW[p*64 + r] = W[p, i0+r]
  int chunk = blockIdx.x;              // 16 i-chunks of 64
  int bf = blockIdx.y;                 // 48
  int i0 = chunk * CHUNK;
  const float* Kb = Kl + (size_t)bf*Nn*Nn + (size_t)i0*Nn;
  const float* Wrow0 = wproj + ((size_t)bf*Nn + i0)*PPAD;
  int tid = threadIdx.x;
  for (int t = tid; t < 16*CHUNK; t += 256) {
    int r = t & (CHUNK-1), p = t >> 6;
    sW[p*CHUNK + r] = Wrow0[r*PPAD + p];
  }
  __syncthreads();
  int j0 = tid * 4;
  float4 acc[16];
  #pragma unroll
  for (int p = 0; p < 16; p++) { acc[p].x = 0.f; acc[p].y = 0.f; acc[p].z = 0.f; acc[p].w = 0.f; }
  const float* kp = Kb + j0;
  float4 kbuf[PFK];
  #pragma unroll
  for (int s = 0; s < PFK; s++) kbuf[s] = *(const float4*)(kp + (size_t)s*Nn);
  for (int ii = 0; ii < CHUNK; ii += PFK) {
    #pragma unroll
    for (int s = 0; s < PFK; s++) {
      float4 k4 = kbuf[s];
      int nxt = (ii + PFK + s) & (CHUNK - 1);   // tail wraps to rows 0..7 (L2-hot, harmless)
      kbuf[s] = *(const float4*)(kp + (size_t)nxt*Nn);
      const float* wrow = &sW[ii + s];           // wave-uniform -> LDS broadcast
      #pragma unroll
      for (int p = 0; p < 16; p++) {
        float wv = wrow[p*CHUNK];
        acc[p].x = fmaf(wv, k4.x, acc[p].x);
        acc[p].y = fmaf(wv, k4.y, acc[p].y);
        acc[p].z = fmaf(wv, k4.z, acc[p].z);
        acc[p].w = fmaf(wv, k4.w, acc[p].w);
      }
    }
  }
  float* tp = tpart + ((size_t)(bf*16 + chunk)*16)*Nn + j0;
  #pragma unroll
  for (int p = 0; p < 16; p++) *(float4*)(tp + (size_t)p*Nn) = acc[p];
}

// ---------------- M pass: src[p] = (1/s) sum_i W[p,i] (M[i,:].Wv)  ----------------
__global__ __launch_bounds__(256, 3) void k_projM(
    const float* __restrict__ Ml, const float* __restrict__ wproj,
    const float* __restrict__ flat, float* __restrict__ srca) {
  __shared__ float sW[16*CHUNK];
  int chunk = blockIdx.x;
  int bf = blockIdx.y;
  int i0 = chunk * CHUNK;
  const float* Mb = Ml + (size_t)bf*Nn*Nn + (size_t)i0*Nn;
  const float* Wp = wproj + (size_t)bf*Nn*PPAD;
  const float* Wrow0 = Wp + (size_t)i0*PPAD;
  int tid = threadIdx.x;
  for (int t = tid; t < 16*CHUNK; t += 256) {
    int r = t & (CHUNK-1), p = t >> 6;
    sW[p*CHUNK + r] = Wrow0[r*PPAD + p];
  }
  // v[r] = sum_q W[q, j0+r] * fl[q]
  float fl[Pp];
  #pragma unroll
  for (int q = 0; q < Pp; q++) fl[q] = flat[bf*Pp + q];
  int j0 = tid * 4;
  float v0, v1, v2, v3;
  {
    float vv[4];
    #pragma unroll
    for (int r = 0; r < 4; r++) {
      const float* row = Wp + (size_t)(j0 + r)*PPAD;
      float s = 0.f;
      #pragma unroll
      for (int q = 0; q < Pp; q++) s = fmaf(row[q], fl[q], s);
      vv[r] = s;
    }
    v0 = vv[0]; v1 = vv[1]; v2 = vv[2]; v3 = vv[3];
  }
  __syncthreads();
  float sa[16];
  #pragma unroll
  for (int p = 0; p < 16; p++) sa[p] = 0.f;
  const float* mp = Mb + j0;
  float4 mbuf[PFK];
  #pragma unroll
  for (int s = 0; s < PFK; s++) mbuf[s] = *(const float4*)(mp + (size_t)s*Nn);
  for (int ii = 0; ii < CHUNK; ii += PFK) {
    #pragma unroll
    for (int s = 0; s < PFK; s++) {
      float4 m4 = mbuf[s];
      int nxt = (ii + PFK + s) & (CHUNK - 1);
      mbuf[s] = *(const float4*)(mp + (size_t)nxt*Nn);
      float tm = m4.x*v0 + m4.y*v1 + m4.z*v2 + m4.w*v3;
      const float* wrow = &sW[ii + s];
      #pragma unroll
      for (int p = 0; p < 16; p++) sa[p] = fmaf(wrow[p*CHUNK], tm, sa[p]);
    }
  }
  int lane = tid & 63;
  #pragma unroll
  for (int p = 0; p < 16; p++) {
    float vq = sa[p];
    #pragma unroll
    for (int off = 32; off > 0; off >>= 1) vq += __shfl_xor(vq, off, 64);
    sa[p] = vq;
  }
  if (lane == 0) {
    #pragma unroll
    for (int p = 0; p < 16; p++) atomicAdd(&srca[bf*16 + p], sa[p] * INV_SCALE);
  }
}

// ---------------- khat[p][q] = INV_SCALE * sum_j (sum_c Tpart[c][p][j]) * W[q][j] ----------------
__global__ __launch_bounds__(256) void k_khat(const float* __restrict__ tpart,
                                              const float* __restrict__ wproj,
                                              float* __restrict__ khat) {
  __shared__ float sT[16*64];          // [p][r]
  __shared__ float sWq[64*PPAD];       // [r][q]
  int jb = blockIdx.x, bf = blockIdx.y;
  int tid = threadIdx.x;
  {
    int id = tid * 4;                  // 4 consecutive floats of one p-row
    int p = id >> 6;
    int r = id & 63;
    const float* base = tpart + ((size_t)(bf*16)*16 + p)*Nn + jb*64 + r;
    float4 s4 = make_float4(0.f, 0.f, 0.f, 0.f);
    #pragma unroll 4
    for (int c = 0; c < 16; c++) {
      float4 t4 = *(const float4*)(base + (size_t)c*16*Nn);
      s4.x += t4.x; s4.y += t4.y; s4.z += t4.z; s4.w += t4.w;
    }
    *(float4*)&sT[p*64 + r] = s4;
  }
  const float* wsrc = wproj + ((size_t)bf*Nn + jb*64)*PPAD;   // 1280 contiguous floats
  for (int t = tid; t < 64*PPAD; t += 256) sWq[t] = wsrc[t];
  __syncthreads();
  for (int o = tid; o < 16*Pp; o += 256) {
    int p = o / Pp, q = o - p*Pp;
    float s = 0.f;
    #pragma unroll
    for (int r = 0; r < 64; r++) s = fmaf(sT[p*64 + r], sWq[r*PPAD + q], s);
    atomicAdd(&khat[(bf*16 + p)*Pp + q], s * INV_SCALE);
  }
}

// ---------------- fallback heavy pass (round-1 version) if workspace too small ----------------
__global__ __launch_bounds__(256, 1) void k_project_fb(
    const float* __restrict__ Kl, const float* __restrict__ Ml,
    const float* __restrict__ wproj, const float* __restrict__ flat,
    float* __restrict__ khat, float* __restrict__ srca) {
  __shared__ float sW[16*CHUNK];
  int chunk = blockIdx.x;
  int bf = blockIdx.y;
  int i0 = chunk * CHUNK;
  const float* Kb = Kl + (size_t)bf*Nn*Nn + (size_t)i0*Nn;
  const float* Mb = Ml + (size_t)bf*Nn*Nn + (size_t)i0*Nn;
  const float* Wp = wproj + (size_t)bf*Nn*PPAD;
  const float* Wrow0 = Wp + (size_t)i0*PPAD;
  int tid = threadIdx.x;
  for (int t = tid; t < 16*CHUNK; t += 256) {
    int r = t & (CHUNK-1), p = t >> 6;
    sW[p*CHUNK + r] = Wrow0[r*PPAD + p];
  }
  float fl[Pp];
  #pragma unroll
  for (int q = 0; q < Pp; q++) fl[q] = flat[bf*Pp + q];
  int j0 = tid * 4;
  float v[4];
  #pragma unroll
  for (int r = 0; r < 4; r++) {
    const float* row = Wp + (size_t)(j0 + r)*PPAD;
    float s = 0.f;
    #pragma unroll
    for (int q = 0; q < Pp; q++) s = fmaf(row[q], fl[q], s);
    v[r] = s;
  }
  __syncthreads();
  float4 acc[16];
  float sa[16];
  #pragma unroll
  for (int p = 0; p < 16; p++) {
    acc[p].x = 0.f; acc[p].y = 0.f; acc[p].z = 0.f; acc[p].w = 0.f;
    sa[p] = 0.f;
  }
  const float* kp = Kb + j0;
  const float* mp = Mb + j0;
  float4 kbuf[PF], mbuf[PF];
  #pragma unroll
  for (int s = 0; s < PF; s++) {
    kbuf[s] = *(const float4*)(kp + (size_t)s*Nn);
    mbuf[s] = *(const float4*)(mp + (size_t)s*Nn);
  }
  for (int ii = 0; ii < CHUNK; ii += PF) {
    #pragma unroll
    for (int s = 0; s < PF; s++) {
      float4 k4 = kbuf[s], m4 = mbuf[s];
      int nxt = (ii + PF + s) & (CHUNK - 1);
      kbuf[s] = *(const float4*)(kp + (size_t)nxt*Nn);
      mbuf[s] = *(const float4*)(mp + (size_t)nxt*Nn);
      float tm = m4.x*v[0] + m4.y*v[1] + m4.z*v[2] + m4.w*v[3];
      const float* wrow = &sW[ii + s];
      #pragma unroll
      for (int p = 0; p < 16; p++) {
        float wv = wrow[p*CHUNK];
        acc[p].x = fmaf(wv, k4.x, acc[p].x);
        acc[p].y = fmaf(wv, k4.y, acc[p].y);
        acc[p].z = fmaf(wv, k4.z, acc[p].z);
        acc[p].w = fmaf(wv, k4.w, acc[p].w);
        sa[p] = fmaf(wv, tm, sa[p]);
      }
    }
  }
  int lane = tid & 63;
  #pragma unroll
  for (int q = 0; q < Pp; q++) {
    float w0 = Wp[(size_t)(j0 + 0)*PPAD + q];
    float w1 = Wp[(size_t)(j0 + 1)*PPAD + q];
    float w2 = Wp[(size_t)(j0 + 2)*PPAD + q];
    float w3 = Wp[(size_t)(j0 + 3)*PPAD + q];
    float pr[16];
    #pragma unroll
    for (int p = 0; p < 16; p++)
      pr[p] = acc[p].x*w0 + acc[p].y*w1 + acc[p].z*w2 + acc[p].w*w3;
    #pragma unroll
    for (int p = 0; p < 16; p++) {
      float vq = pr[p];
      #pragma unroll
      for (int off = 32; off > 0; off >>= 1) vq += __shfl_xor(vq, off, 64);
      pr[p] = vq;
    }
    if (lane == 0) {
      #pragma unroll
      for (int p = 0; p < 16; p++)
        atomicAdd(&khat[(bf*16 + p)*Pp + q], pr[p] * INV_SCALE);
    }
  }
  #pragma unroll
  for (int p = 0; p < 16; p++) {
    float vq = sa[p];
    #pragma unroll
    for (int off = 32; off > 0; off >>= 1) vq += __shfl_xor(vq, off, 64);
    sa[p] = vq;
  }
  if (lane == 0) {
    #pragma unroll
    for (int p = 0; p < 16; p++) atomicAdd(&srca[bf*16 + p], sa[p] * INV_SCALE);
  }
}

// ---------------- damped fixed-point solver v4: one edge per lane, wave-uniform weights ----
// 384 threads = 6 waves: wave -> (edge-group 0..2, d-half 0..1). Each lane owns ONE edge and
// serially accumulates its 32-d flux half in 3 registers: NO shfl, no per-lane weight state.
// Weight rows wpack[b][d][16] are read at wave-uniform addresses (readfirstlane-pinned base)
// -> scalar/broadcast loads on a separate pipe; live set ~40 VGPR, nothing to spill.
// Update phase sums the two d-half partials from LDS. 2 barriers/iter.
__global__ __launch_bounds__(384, 1) void k_solve(
    const float* __restrict__ khat, const float* __restrict__ srca,
    const float* __restrict__ wpack, const float* __restrict__ u_init,
    float* __restrict__ ubuf) {
  int b = blockIdx.x;
  __shared__ float u4[Pp*4];           // u padded to float4 rows
  __shared__ float fluxp[2][Ee*3];     // d-half partial fluxes
  __shared__ float sK[Fc*16*Pp];
  __shared__ float ssrc[Fc*16];
  int tid = threadIdx.x;
  for (int t = tid; t < Fc*16*Pp; t += 384) sK[t] = khat[b*Fc*16*Pp + t];
  if (tid < 48) ssrc[tid] = srca[b*48 + tid];
  if (tid < 57) u4[(tid/3)*4 + (tid%3)] = u_init[b*57 + tid];
  if (tid < Pp) u4[tid*4 + 3] = 0.f;
  __syncthreads();

  int wave = tid >> 6, lane = tid & 63;
  int eg = wave % 3, dh = wave / 3;
  int e = eg*64 + lane;
  bool active = (e < Ee);
  int ei = 0, ej = 0;
  {
    int r = active ? e : 0, i = 0;
    while (r >= 18 - i) { r -= 18 - i; i++; }
    ei = i; ej = i + 1 + r;
  }
  // wave-uniform weight base (pinned to SGPR so the d-loop reads are scalar loads)
  const float* wpk = wpack + (size_t)b*WPACK_B
                   + (size_t)__builtin_amdgcn_readfirstlane(dh * 32 * 16);
  bool upd = (tid < 57);
  int up = tid / 3, uf = tid - (tid/3)*3;

  for (int it = 0; it < ITERS; it++) {
    if (active) {
      float4 ua = *(const float4*)&u4[ei*4];
      float4 ub = *(const float4*)&u4[ej*4];
      float fl0 = 0.f, fl1 = 0.f, fl2 = 0.f;
      #pragma unroll 8
      for (int dd = 0; dd < 32; dd++) {
        const float* s = wpk + dd*16;
        float4 sA = *(const float4*)(s);       // 2*W1[0..3]
        float4 sB = *(const float4*)(s + 4);   // 2*W1[4..5], 2*bz, pad
        float4 sC = *(const float4*)(s + 8);   // W2[0..2], pad
        float pre = sB.z;                      // 2*bz
        pre = fmaf(ua.x, sA.x, pre);
        pre = fmaf(ua.y, sA.y, pre);
        pre = fmaf(ua.z, sA.z, pre);
        pre = fmaf(ub.x, sA.w, pre);
        pre = fmaf(ub.y, sB.x, pre);
        pre = fmaf(ub.z, sB.y, pre);
        float t = __expf(pre);                 // exp(2x); saturates safely at +-inf
        float rr = __builtin_amdgcn_rcpf(t + 1.f);
        float th = fmaf(-2.f, rr, 1.f);        // tanh(x)
        fl0 = fmaf(th, sC.x, fl0);
        fl1 = fmaf(th, sC.y, fl1);
        fl2 = fmaf(th, sC.z, fl2);
      }
      fluxp[dh][e*3 + 0] = fl0;
      fluxp[dh][e*3 + 1] = fl1;
      fluxp[dh][e*3 + 2] = fl2;
    }
    __syncthreads();
    if (upd) {
      float u_old = u4[up*4 + uf];
      float r_;
      if (up < 16) {
        float diff = 0.f;
        const float* kr = &sK[(uf*16 + up)*Pp];
        #pragma unroll
        for (int q = 0; q < Pp; q++) diff = fmaf(kr[q], u4[q*4 + uf], diff);
        float ft = 0.f;
        #pragma unroll
        for (int o = 0; o < Pp; o++) {
          if (o == up) continue;
          int i_ = (o < up) ? o : up;
          int j_ = (o < up) ? up : o;
          int eidx = i_*Pp - (i_*(i_+1))/2 + (j_ - i_ - 1);
          float sgn = (o < up) ? 1.f : -1.f;
          ft += sgn * (fluxp[0][eidx*3 + uf] + fluxp[1][eidx*3 + uf]);
        }
        r_ = diff - ssrc[uf*16 + up] - ft;
      } else {
        r_ = u_old - ((up == 16) ? 1.f : 0.f);
      }
      u4[up*4 + uf] = u_old - 0.1f * r_;
    }
    __syncthreads();
  }
  if (tid < 57) ubuf[b*57 + tid] = u4[(tid/3)*4 + (tid%3)];
}

// ---------------- u_fine = einsum('bpif,bpf->bif') ----------------
__global__ __launch_bounds__(256) void k_out(const float* __restrict__ wproj,
                                             const float* __restrict__ ubuf,
                                             float* __restrict__ out) {
  __shared__ float u_s[57];
  int b = blockIdx.y;
  int i = blockIdx.x*256 + threadIdx.x;
  if (threadIdx.x < 57) u_s[threadIdx.x] = ubuf[b*57 + threadIdx.x];
  __syncthreads();
  #pragma unroll
  for (int f = 0; f < Fc; f++) {
    const float* row = wproj + ((size_t)(b*Fc + f)*Nn + i)*PPAD;
    float s = 0.f;
    #pragma unroll
    for (int p = 0; p < Pp; p++) s = fmaf(row[p], u_s[p*3 + f], s);
    out[((size_t)b*Nn + i)*Fc + f] = s;
  }
}

extern "C" void kernel_launch(void* const* d_in, const int* in_sizes, int n_in,
                              void* d_out, int out_size, void* d_ws, size_t ws_size,
                              hipStream_t stream) {
  const float* in_tokens = (const float*)d_in[0];
  const float* K_list    = (const float*)d_in[1];
  const float* M_list    = (const float*)d_in[2];
  const int*   dnodes    = (const int*)d_in[3];
  const float* bvals     = (const float*)d_in[4];
  const float* u_init    = (const float*)d_in[5];
  const float* W_enc     = (const float*)d_in[6];
  const float* b_enc     = (const float*)d_in[7];
  const float* W_src     = (const float*)d_in[8];
  const float* b_src     = (const float*)d_in[9];
  const float* W_pou     = (const float*)d_in[10];
  const float* Wf1       = (const float*)d_in[11];
  const float* Wz        = (const float*)d_in[12];
  const float* bfv       = (const float*)d_in[13];
  const float* Wf2       = (const float*)d_in[14];
  float* ws  = (float*)d_ws;
  float* out = (float*)d_out;

  float* WPROJ = ws + OFF_WPROJ;
  float* FFULL = ws + OFF_FFULL;
  float* FLAT  = ws + OFF_FLAT;
  float* UBUF  = ws + OFF_UBUF;
  float* BVALS = ws + OFF_BVALS;
  float* ZACC  = ws + OFF_ZACC;
  float* KHAT  = ws + OFF_KHAT;
  float* SRC   = ws + OFF_SRC;
  float* WPACK = ws + OFF_WPACK;
  float* TPART = ws + OFF_TPART;

  hipMemsetAsync(ws + OFF_BVALS, 0, (size_t)ZERO_FLOATS * sizeof(float), stream);
  k_scatter<<<1, 1024, 0, stream>>>(dnodes, bvals, BVALS);
  k_encode<<<128, 128, 0, stream>>>(in_tokens, W_enc, b_enc, W_src, b_src, W_pou,
                                    BVALS, WPROJ, FFULL, ZACC);
  k_wpack<<<Bn, 64, 0, stream>>>(ZACC, Wz, bfv, Wf1, Wf2, WPACK);
  k_flat<<<Bn*Fc, 256, 0, stream>>>(WPROJ, FFULL, FLAT);
  if (ws_size >= (size_t)NEED_FLOATS * sizeof(float)) {
    k_projT<<<dim3(Nn/CHUNK, Bn*Fc), 256, 0, stream>>>(K_list, WPROJ, TPART);
    k_projM<<<dim3(Nn/CHUNK, Bn*Fc), 256, 0, stream>>>(M_list, WPROJ, FLAT, SRC);
    k_khat<<<dim3(16, Bn*Fc), 256, 0, stream>>>(TPART, WPROJ, KHAT);
  } else {
    k_project_fb<<<dim3(Nn/CHUNK, Bn*Fc), 256, 0, stream>>>(K_list, M_list, WPROJ, FLAT, KHAT, SRC);
  }
  k_solve<<<Bn, 384, 0, stream>>>(KHAT, SRC, WPACK, u_init, UBUF);
  k_out<<<dim3(Nn/256, Bn), 256, 0, stream>>>(WPROJ, UBUF, out);
}

// Round 7
// 698.856 us; speedup vs baseline: 1.1272x; 1.0498x over previous
//
#include <hip/hip_runtime.h>

#define Bn 16
#define Nn 1024
#define DIN 32
#define DZ 64
#define Fc 3
#define Pp 19
#define PPAD 20
#define Ee 171
#define ITERS 50
#define INV_SCALE (19.0f/1024.0f)
#define CHUNK 64
#define PF 4
#define PFK 8
#define WPACK_B 1024   // 64 d x 16 floats per batch

// workspace offsets (in floats)
#define OFF_WPROJ 0         // [B][F][N][PPAD]  983040
#define OFF_FFULL 983040    // [B][N][F]        49152
#define OFF_FLAT  1033216   // [B][F][19]       912
#define OFF_UBUF  1034128   // [B][57]          912
#define OFF_BVALS 1035040   // [B][N][F]        49152   -- zero region start
#define OFF_ZACC  1084192   // [B][64]          1024
#define OFF_KHAT  1085216   // [B][F][16][19]   14592
#define OFF_SRC   1099808   // [B][F][16]       768
#define ZERO_FLOATS 65536   // BVALS+ZACC+KHAT+SRC contiguous
#define OFF_WPACK 1100576   // [B][64][16]      16384
#define OFF_TPART 1116960   // [B*F][16 chunks][16 p][1024 j]  12582912 floats (48 MB)
#define NEED_FLOATS (OFF_TPART + 48*16*16*1024)

// ---------------- scatter boundary_vals (parallel, deterministic last-wins) ----------------
__global__ __launch_bounds__(1024) void k_scatter(const int* __restrict__ nodes,
                                                  const float* __restrict__ bvals,
                                                  float* __restrict__ bfull) {
  __shared__ int sn[1024];
  int tid = threadIdx.x;
  sn[tid] = nodes[tid];
  __syncthreads();
  int b = tid >> 6, j = tid & 63;
  int node = sn[tid];
  bool win = true;
  for (int j2 = j + 1; j2 < 64; j2++)
    if (sn[(b << 6) | j2] == node) { win = false; break; }
  if (win) {
    #pragma unroll
    for (int f = 0; f < Fc; f++)
      bfull[((size_t)b*Nn + node)*Fc + f] = bvals[(size_t)tid*Fc + f];
  }
}

// ---------------- encoder + POU softmax + f_full + zacc partials ----------------
__global__ __launch_bounds__(128) void k_encode(
    const float* __restrict__ x, const float* __restrict__ Wenc, const float* __restrict__ benc,
    const float* __restrict__ Wsrc, const float* __restrict__ bsrc, const float* __restrict__ Wpou,
    const float* __restrict__ bfull, float* __restrict__ wproj, float* __restrict__ ffull,
    float* __restrict__ zacc) {
  __shared__ float sWenc[DIN*DZ];
  __shared__ float sWpou[DZ*57];
  __shared__ float sWsrc[DZ*Fc];
  int tid = threadIdx.x;
  for (int t = tid; t < DIN*DZ; t += 128) sWenc[t] = Wenc[t];
  for (int t = tid; t < DZ*57; t += 128) sWpou[t] = Wpou[t];
  for (int t = tid; t < DZ*Fc; t += 128) sWsrc[t] = Wsrc[t];
  __syncthreads();
  int g = blockIdx.x*128 + tid;         // b*N + i
  int b = g >> 10, i = g & 1023;
  float xr[DIN];
  const float* xp = x + (size_t)g*DIN;
  #pragma unroll
  for (int k = 0; k < DIN; k += 4) {
    float4 t4 = *(const float4*)(xp + k);
    xr[k] = t4.x; xr[k+1] = t4.y; xr[k+2] = t4.z; xr[k+3] = t4.w;
  }
  float l[57];
  #pragma unroll
  for (int o = 0; o < 57; o++) l[o] = 0.f;
  float ff[3] = {bsrc[0], bsrc[1], bsrc[2]};
  int lane = tid & 63;
  for (int d = 0; d < DZ; d++) {
    float zd = benc[d];
    #pragma unroll
    for (int k = 0; k < DIN; k++) zd = fmaf(xr[k], sWenc[k*DZ + d], zd);
    zd = tanhf(zd);
    #pragma unroll
    for (int o = 0; o < 57; o++) l[o] = fmaf(zd, sWpou[d*57 + o], l[o]);
    #pragma unroll
    for (int f = 0; f < Fc; f++) ff[f] = fmaf(zd, sWsrc[d*Fc + f], ff[f]);
    float zs = zd;
    #pragma unroll
    for (int off = 32; off > 0; off >>= 1) zs += __shfl_xor(zs, off, 64);
    if (lane == 0) atomicAdd(&zacc[b*DZ + d], zs);
  }
  #pragma unroll
  for (int f = 0; f < Fc; f++) ffull[(size_t)g*Fc + f] = ff[f];
  #pragma unroll
  for (int f = 0; f < Fc; f++) {
    float bv = bfull[(size_t)g*Fc + f];
    l[16*3+f] += bv; l[17*3+f] += bv; l[18*3+f] += bv;
  }
  #pragma unroll
  for (int f = 0; f < Fc; f++) {
    float m = l[f];
    #pragma unroll
    for (int p = 1; p < Pp; p++) m = fmaxf(m, l[p*3+f]);
    float ex[Pp]; float s = 0.f;
    #pragma unroll
    for (int p = 0; p < Pp; p++) { ex[p] = __expf(l[p*3+f] - m); s += ex[p]; }
    float inv = 1.f / s;
    float* wp = wproj + ((size_t)(b*Fc + f)*Nn + i)*PPAD;
    #pragma unroll
    for (int p = 0; p < Pp; p++) wp[p] = ex[p]*inv;
  }
}

// ---------------- f_latent[b,f,q] = (1/scale) sum_i W[q,i] f_full[i,f] ----------------
__global__ __launch_bounds__(256) void k_flat(const float* __restrict__ wproj,
                                              const float* __restrict__ ffull,
                                              float* __restrict__ flat) {
  int bf = blockIdx.x;                 // b*3+f
  int b = bf / 3, f = bf % 3;
  float acc[Pp];
  #pragma unroll
  for (int q = 0; q < Pp; q++) acc[q] = 0.f;
  for (int i = threadIdx.x; i < Nn; i += 256) {
    float fv = ffull[((size_t)b*Nn + i)*Fc + f];
    const float* row = wproj + ((size_t)bf*Nn + i)*PPAD;
    #pragma unroll
    for (int q = 0; q < Pp; q++) acc[q] = fmaf(row[q], fv, acc[q]);
  }
  #pragma unroll
  for (int q = 0; q < Pp; q++) {
    float v = acc[q];
    #pragma unroll
    for (int off = 32; off > 0; off >>= 1) v += __shfl_xor(v, off, 64);
    acc[q] = v;
  }
  __shared__ float red[4][Pp];
  int wave = threadIdx.x >> 6, lane = threadIdx.x & 63;
  if (lane == 0) {
    #pragma unroll
    for (int q = 0; q < Pp; q++) red[wave][q] = acc[q];
  }
  __syncthreads();
  if (threadIdx.x < Pp) {
    float s = red[0][threadIdx.x] + red[1][threadIdx.x] + red[2][threadIdx.x] + red[3][threadIdx.x];
    flat[bf*Pp + threadIdx.x] = s * INV_SCALE;
  }
}

// ---------------- pack flux-MLP weights per (b, d): {2*W1[0..5,d], 2*bz, pad, W2[d,0..2], pad} ---
__global__ __launch_bounds__(64) void k_wpack(
    const float* __restrict__ zacc, const float* __restrict__ Wz,
    const float* __restrict__ bfv, const float* __restrict__ Wf1,
    const float* __restrict__ Wf2, float* __restrict__ wpack) {
  int b = blockIdx.x, d = threadIdx.x;
  float s = 0.f;
  for (int k = 0; k < DZ; k++) s = fmaf(zacc[b*DZ + k], Wz[k*DZ + d], s);
  float bz = bfv[d] + s * (1.f/1024.f);
  float* w = wpack + (size_t)b*WPACK_B + d*16;
  #pragma unroll
  for (int k = 0; k < 6; k++) w[k] = 2.f * Wf1[k*DZ + d];
  w[6] = 2.f * bz;
  w[7] = 0.f;
  w[8]  = Wf2[d*3 + 0];
  w[9]  = Wf2[d*3 + 1];
  w[10] = Wf2[d*3 + 2];
  w[11] = 0.f; w[12] = 0.f; w[13] = 0.f; w[14] = 0.f; w[15] = 0.f;
}

// ---------------- K pass: T_chunk[p, j] = sum_i W[p,i] K[i,j]  (coalesced float4 out) ----------------
__global__ __launch_bounds__(256, 3) void k_projT(
    const float* __restrict__ Kl, const float* __restrict__ wproj,
    float* __restrict__ tpart) {
  __shared__ float sW[16*CHUNK];       // sW[p*64 + r] = W[p, i0+r]
  int chunk = blockIdx.x;              // 16 i-chunks of 64
  int bf = blockIdx.y;                 // 48
  int i0 = chunk * CHUNK;
  const float* Kb = Kl + (size_t)bf*Nn*Nn + (size_t)i0*Nn;
  const float* Wrow0 = wproj + ((size_t)bf*Nn + i0)*PPAD;
  int tid = threadIdx.x;
  for (int t = tid; t < 16*CHUNK; t += 256) {
    int r = t & (CHUNK-1), p = t >> 6;
    sW[p*CHUNK + r] = Wrow0[r*PPAD + p];
  }
  __syncthreads();
  int j0 = tid * 4;
  float4 acc[16];
  #pragma unroll
  for (int p = 0; p < 16; p++) { acc[p].x = 0.f; acc[p].y = 0.f; acc[p].z = 0.f; acc[p].w = 0.f; }
  const float* kp = Kb + j0;
  float4 kbuf[PFK];
  #pragma unroll
  for (int s = 0; s < PFK; s++) kbuf[s] = *(const float4*)(kp + (size_t)s*Nn);
  for (int ii = 0; ii < CHUNK; ii += PFK) {
    #pragma unroll
    for (int s = 0; s < PFK; s++) {
      float4 k4 = kbuf[s];
      int nxt = (ii + PFK + s) & (CHUNK - 1);   // tail wraps to rows 0..7 (L2-hot, harmless)
      kbuf[s] = *(const float4*)(kp + (size_t)nxt*Nn);
      const float* wrow = &sW[ii + s];           // wave-uniform -> LDS broadcast
      #pragma unroll
      for (int p = 0; p < 16; p++) {
        float wv = wrow[p*CHUNK];
        acc[p].x = fmaf(wv, k4.x, acc[p].x);
        acc[p].y = fmaf(wv, k4.y, acc[p].y);
        acc[p].z = fmaf(wv, k4.z, acc[p].z);
        acc[p].w = fmaf(wv, k4.w, acc[p].w);
      }
    }
  }
  float* tp = tpart + ((size_t)(bf*16 + chunk)*16)*Nn + j0;
  #pragma unroll
  for (int p = 0; p < 16; p++) *(float4*)(tp + (size_t)p*Nn) = acc[p];
}

// ---------------- M pass: src[p] = (1/s) sum_i W[p,i] (M[i,:].Wv)  ----------------
__global__ __launch_bounds__(256, 3) void k_projM(
    const float* __restrict__ Ml, const float* __restrict__ wproj,
    const float* __restrict__ flat, float* __restrict__ srca) {
  __shared__ float sW[16*CHUNK];
  int chunk = blockIdx.x;
  int bf = blockIdx.y;
  int i0 = chunk * CHUNK;
  const float* Mb = Ml + (size_t)bf*Nn*Nn + (size_t)i0*Nn;
  const float* Wp = wproj + (size_t)bf*Nn*PPAD;
  const float* Wrow0 = Wp + (size_t)i0*PPAD;
  int tid = threadIdx.x;
  for (int t = tid; t < 16*CHUNK; t += 256) {
    int r = t & (CHUNK-1), p = t >> 6;
    sW[p*CHUNK + r] = Wrow0[r*PPAD + p];
  }
  // v[r] = sum_q W[q, j0+r] * fl[q]
  float fl[Pp];
  #pragma unroll
  for (int q = 0; q < Pp; q++) fl[q] = flat[bf*Pp + q];
  int j0 = tid * 4;
  float v0, v1, v2, v3;
  {
    float vv[4];
    #pragma unroll
    for (int r = 0; r < 4; r++) {
      const float* row = Wp + (size_t)(j0 + r)*PPAD;
      float s = 0.f;
      #pragma unroll
      for (int q = 0; q < Pp; q++) s = fmaf(row[q], fl[q], s);
      vv[r] = s;
    }
    v0 = vv[0]; v1 = vv[1]; v2 = vv[2]; v3 = vv[3];
  }
  __syncthreads();
  float sa[16];
  #pragma unroll
  for (int p = 0; p < 16; p++) sa[p] = 0.f;
  const float* mp = Mb + j0;
  float4 mbuf[PFK];
  #pragma unroll
  for (int s = 0; s < PFK; s++) mbuf[s] = *(const float4*)(mp + (size_t)s*Nn);
  for (int ii = 0; ii < CHUNK; ii += PFK) {
    #pragma unroll
    for (int s = 0; s < PFK; s++) {
      float4 m4 = mbuf[s];
      int nxt = (ii + PFK + s) & (CHUNK - 1);
      mbuf[s] = *(const float4*)(mp + (size_t)nxt*Nn);
      float tm = m4.x*v0 + m4.y*v1 + m4.z*v2 + m4.w*v3;
      const float* wrow = &sW[ii + s];
      #pragma unroll
      for (int p = 0; p < 16; p++) sa[p] = fmaf(wrow[p*CHUNK], tm, sa[p]);
    }
  }
  int lane = tid & 63;
  #pragma unroll
  for (int p = 0; p < 16; p++) {
    float vq = sa[p];
    #pragma unroll
    for (int off = 32; off > 0; off >>= 1) vq += __shfl_xor(vq, off, 64);
    sa[p] = vq;
  }
  if (lane == 0) {
    #pragma unroll
    for (int p = 0; p < 16; p++) atomicAdd(&srca[bf*16 + p], sa[p] * INV_SCALE);
  }
}

// ---------------- khat[p][q] = INV_SCALE * sum_j (sum_c Tpart[c][p][j]) * W[q][j] ----------------
__global__ __launch_bounds__(256) void k_khat(const float* __restrict__ tpart,
                                              const float* __restrict__ wproj,
                                              float* __restrict__ khat) {
  __shared__ float sT[16*64];          // [p][r]
  __shared__ float sWq[64*PPAD];       // [r][q]
  int jb = blockIdx.x, bf = blockIdx.y;
  int tid = threadIdx.x;
  {
    int id = tid * 4;                  // 4 consecutive floats of one p-row
    int p = id >> 6;
    int r = id & 63;
    const float* base = tpart + ((size_t)(bf*16)*16 + p)*Nn + jb*64 + r;
    float4 s4 = make_float4(0.f, 0.f, 0.f, 0.f);
    #pragma unroll 4
    for (int c = 0; c < 16; c++) {
      float4 t4 = *(const float4*)(base + (size_t)c*16*Nn);
      s4.x += t4.x; s4.y += t4.y; s4.z += t4.z; s4.w += t4.w;
    }
    *(float4*)&sT[p*64 + r] = s4;
  }
  const float* wsrc = wproj + ((size_t)bf*Nn + jb*64)*PPAD;   // 1280 contiguous floats
  for (int t = tid; t < 64*PPAD; t += 256) sWq[t] = wsrc[t];
  __syncthreads();
  for (int o = tid; o < 16*Pp; o += 256) {
    int p = o / Pp, q = o - p*Pp;
    float s = 0.f;
    #pragma unroll
    for (int r = 0; r < 64; r++) s = fmaf(sT[p*64 + r], sWq[r*PPAD + q], s);
    atomicAdd(&khat[(bf*16 + p)*Pp + q], s * INV_SCALE);
  }
}

// ---------------- fallback heavy pass (round-1 version) if workspace too small ----------------
__global__ __launch_bounds__(256, 1) void k_project_fb(
    const float* __restrict__ Kl, const float* __restrict__ Ml,
    const float* __restrict__ wproj, const float* __restrict__ flat,
    float* __restrict__ khat, float* __restrict__ srca) {
  __shared__ float sW[16*CHUNK];
  int chunk = blockIdx.x;
  int bf = blockIdx.y;
  int i0 = chunk * CHUNK;
  const float* Kb = Kl + (size_t)bf*Nn*Nn + (size_t)i0*Nn;
  const float* Mb = Ml + (size_t)bf*Nn*Nn + (size_t)i0*Nn;
  const float* Wp = wproj + (size_t)bf*Nn*PPAD;
  const float* Wrow0 = Wp + (size_t)i0*PPAD;
  int tid = threadIdx.x;
  for (int t = tid; t < 16*CHUNK; t += 256) {
    int r = t & (CHUNK-1), p = t >> 6;
    sW[p*CHUNK + r] = Wrow0[r*PPAD + p];
  }
  float fl[Pp];
  #pragma unroll
  for (int q = 0; q < Pp; q++) fl[q] = flat[bf*Pp + q];
  int j0 = tid * 4;
  float v[4];
  #pragma unroll
  for (int r = 0; r < 4; r++) {
    const float* row = Wp + (size_t)(j0 + r)*PPAD;
    float s = 0.f;
    #pragma unroll
    for (int q = 0; q < Pp; q++) s = fmaf(row[q], fl[q], s);
    v[r] = s;
  }
  __syncthreads();
  float4 acc[16];
  float sa[16];
  #pragma unroll
  for (int p = 0; p < 16; p++) {
    acc[p].x = 0.f; acc[p].y = 0.f; acc[p].z = 0.f; acc[p].w = 0.f;
    sa[p] = 0.f;
  }
  const float* kp = Kb + j0;
  const float* mp = Mb + j0;
  float4 kbuf[PF], mbuf[PF];
  #pragma unroll
  for (int s = 0; s < PF; s++) {
    kbuf[s] = *(const float4*)(kp + (size_t)s*Nn);
    mbuf[s] = *(const float4*)(mp + (size_t)s*Nn);
  }
  for (int ii = 0; ii < CHUNK; ii += PF) {
    #pragma unroll
    for (int s = 0; s < PF; s++) {
      float4 k4 = kbuf[s], m4 = mbuf[s];
      int nxt = (ii + PF + s) & (CHUNK - 1);
      kbuf[s] = *(const float4*)(kp + (size_t)nxt*Nn);
      mbuf[s] = *(const float4*)(mp + (size_t)nxt*Nn);
      float tm = m4.x*v[0] + m4.y*v[1] + m4.z*v[2] + m4.w*v[3];
      const float* wrow = &sW[ii + s];
      #pragma unroll
      for (int p = 0; p < 16; p++) {
        float wv = wrow[p*CHUNK];
        acc[p].x = fmaf(wv, k4.x, acc[p].x);
        acc[p].y = fmaf(wv, k4.y, acc[p].y);
        acc[p].z = fmaf(wv, k4.z, acc[p].z);
        acc[p].w = fmaf(wv, k4.w, acc[p].w);
        sa[p] = fmaf(wv, tm, sa[p]);
      }
    }
  }
  int lane = tid & 63;
  #pragma unroll
  for (int q = 0; q < Pp; q++) {
    float w0 = Wp[(size_t)(j0 + 0)*PPAD + q];
    float w1 = Wp[(size_t)(j0 + 1)*PPAD + q];
    float w2 = Wp[(size_t)(j0 + 2)*PPAD + q];
    float w3 = Wp[(size_t)(j0 + 3)*PPAD + q];
    float pr[16];
    #pragma unroll
    for (int p = 0; p < 16; p++)
      pr[p] = acc[p].x*w0 + acc[p].y*w1 + acc[p].z*w2 + acc[p].w*w3;
    #pragma unroll
    for (int p = 0; p < 16; p++) {
      float vq = pr[p];
      #pragma unroll
      for (int off = 32; off > 0; off >>= 1) vq += __shfl_xor(vq, off, 64);
      pr[p] = vq;
    }
    if (lane == 0) {
      #pragma unroll
      for (int p = 0; p < 16; p++)
        atomicAdd(&khat[(bf*16 + p)*Pp + q], pr[p] * INV_SCALE);
    }
  }
  #pragma unroll
  for (int p = 0; p < 16; p++) {
    float vq = sa[p];
    #pragma unroll
    for (int off = 32; off > 0; off >>= 1) vq += __shfl_xor(vq, off, 64);
    sa[p] = vq;
  }
  if (lane == 0) {
    #pragma unroll
    for (int p = 0; p < 16; p++) atomicAdd(&srca[bf*16 + p], sa[p] * INV_SCALE);
  }
}

// ---------------- damped fixed-point solver v5: 12 waves (3/SIMD) for TLP ----------------
// 768 threads: wave -> (edge-group 0..2, d-quarter 0..3). One edge per lane, 16 d's per lane,
// 48 uniform-address float4 loads per lane per iter hidden by 3-waves/SIMD interleave.
// Flux partials in 4 deterministic LDS slabs (no float atomics); 57-lane update sums them.
__global__ __launch_bounds__(768, 1) void k_solve(
    const float* __restrict__ khat, const float* __restrict__ srca,
    const float* __restrict__ wpack, const float* __restrict__ u_init,
    float* __restrict__ ubuf) {
  int b = blockIdx.x;
  __shared__ float u4[Pp*4];           // u padded to float4 rows
  __shared__ float fluxp[4][Ee*Fc];    // d-quarter partial fluxes
  __shared__ float sK[Fc*16*Pp];
  __shared__ float ssrc[Fc*16];
  int tid = threadIdx.x;
  for (int t = tid; t < Fc*16*Pp; t += 768) sK[t] = khat[b*Fc*16*Pp + t];
  if (tid < 48) ssrc[tid] = srca[b*48 + tid];
  if (tid < 57) u4[(tid/3)*4 + (tid%3)] = u_init[b*57 + tid];
  if (tid < Pp) u4[tid*4 + 3] = 0.f;
  __syncthreads();

  int wv = tid >> 6, lane = tid & 63;
  int eg = wv % 3, dq = wv / 3;        // dq 0..3, 16 d's each
  int e = eg*64 + lane;
  bool active = (e < Ee);
  int ei = 0, ej = 0;
  {
    int r = active ? e : 0, i = 0;
    while (r >= 18 - i) { r -= 18 - i; i++; }
    ei = i; ej = i + 1 + r;
  }
  // wave-uniform weight base (pinned so d-loop addresses are scalar-friendly)
  const float* wpk = wpack + (size_t)b*WPACK_B
                   + (size_t)__builtin_amdgcn_readfirstlane(dq * 16 * 16);
  bool upd = (tid < 57);
  int up = tid / 3, uf = tid - (tid/3)*3;

  for (int it = 0; it < ITERS; it++) {
    if (active) {
      float4 ua = *(const float4*)&u4[ei*4];
      float4 ub = *(const float4*)&u4[ej*4];
      float fl0 = 0.f, fl1 = 0.f, fl2 = 0.f;
      #pragma unroll 4
      for (int dd = 0; dd < 16; dd++) {
        const float* s = wpk + dd*16;
        float4 sA = *(const float4*)(s);       // 2*W1[0..3]
        float4 sB = *(const float4*)(s + 4);   // 2*W1[4..5], 2*bz, pad
        float4 sC = *(const float4*)(s + 8);   // W2[0..2], pad
        float pre = sB.z;                      // 2*bz
        pre = fmaf(ua.x, sA.x, pre);
        pre = fmaf(ua.y, sA.y, pre);
        pre = fmaf(ua.z, sA.z, pre);
        pre = fmaf(ub.x, sA.w, pre);
        pre = fmaf(ub.y, sB.x, pre);
        pre = fmaf(ub.z, sB.y, pre);
        float t = __expf(pre);                 // exp(2x); saturates safely at +-inf
        float rr = __builtin_amdgcn_rcpf(t + 1.f);
        float th = fmaf(-2.f, rr, 1.f);        // tanh(x)
        fl0 = fmaf(th, sC.x, fl0);
        fl1 = fmaf(th, sC.y, fl1);
        fl2 = fmaf(th, sC.z, fl2);
      }
      fluxp[dq][e*3 + 0] = fl0;
      fluxp[dq][e*3 + 1] = fl1;
      fluxp[dq][e*3 + 2] = fl2;
    }
    __syncthreads();
    if (upd) {
      float u_old = u4[up*4 + uf];
      float r_;
      if (up < 16) {
        float diff = 0.f;
        const float* kr = &sK[(uf*16 + up)*Pp];
        #pragma unroll
        for (int q = 0; q < Pp; q++) diff = fmaf(kr[q], u4[q*4 + uf], diff);
        float ft = 0.f;
        #pragma unroll
        for (int o = 0; o < Pp; o++) {
          if (o == up) continue;
          int i_ = (o < up) ? o : up;
          int j_ = (o < up) ? up : o;
          int eidx = i_*Pp - (i_*(i_+1))/2 + (j_ - i_ - 1);
          float sgn = (o < up) ? 1.f : -1.f;
          int fo = eidx*3 + uf;
          ft += sgn * (fluxp[0][fo] + fluxp[1][fo] + fluxp[2][fo] + fluxp[3][fo]);
        }
        r_ = diff - ssrc[uf*16 + up] - ft;
      } else {
        r_ = u_old - ((up == 16) ? 1.f : 0.f);
      }
      u4[up*4 + uf] = u_old - 0.1f * r_;
    }
    __syncthreads();
  }
  if (tid < 57) ubuf[b*57 + tid] = u4[(tid/3)*4 + (tid%3)];
}

// ---------------- u_fine = einsum('bpif,bpf->bif') ----------------
__global__ __launch_bounds__(256) void k_out(const float* __restrict__ wproj,
                                             const float* __restrict__ ubuf,
                                             float* __restrict__ out) {
  __shared__ float u_s[57];
  int b = blockIdx.y;
  int i = blockIdx.x*256 + threadIdx.x;
  if (threadIdx.x < 57) u_s[threadIdx.x] = ubuf[b*57 + threadIdx.x];
  __syncthreads();
  #pragma unroll
  for (int f = 0; f < Fc; f++) {
    const float* row = wproj + ((size_t)(b*Fc + f)*Nn + i)*PPAD;
    float s = 0.f;
    #pragma unroll
    for (int p = 0; p < Pp; p++) s = fmaf(row[p], u_s[p*3 + f], s);
    out[((size_t)b*Nn + i)*Fc + f] = s;
  }
}

extern "C" void kernel_launch(void* const* d_in, const int* in_sizes, int n_in,
                              void* d_out, int out_size, void* d_ws, size_t ws_size,
                              hipStream_t stream) {
  const float* in_tokens = (const float*)d_in[0];
  const float* K_list    = (const float*)d_in[1];
  const float* M_list    = (const float*)d_in[2];
  const int*   dnodes    = (const int*)d_in[3];
  const float* bvals     = (const float*)d_in[4];
  const float* u_init    = (const float*)d_in[5];
  const float* W_enc     = (const float*)d_in[6];
  const float* b_enc     = (const float*)d_in[7];
  const float* W_src     = (const float*)d_in[8];
  const float* b_src     = (const float*)d_in[9];
  const float* W_pou     = (const float*)d_in[10];
  const float* Wf1       = (const float*)d_in[11];
  const float* Wz        = (const float*)d_in[12];
  const float* bfv       = (const float*)d_in[13];
  const float* Wf2       = (const float*)d_in[14];
  float* ws  = (float*)d_ws;
  float* out = (float*)d_out;

  float* WPROJ = ws + OFF_WPROJ;
  float* FFULL = ws + OFF_FFULL;
  float* FLAT  = ws + OFF_FLAT;
  float* UBUF  = ws + OFF_UBUF;
  float* BVALS = ws + OFF_BVALS;
  float* ZACC  = ws + OFF_ZACC;
  float* KHAT  = ws + OFF_KHAT;
  float* SRC   = ws + OFF_SRC;
  float* WPACK = ws + OFF_WPACK;
  float* TPART = ws + OFF_TPART;

  hipMemsetAsync(ws + OFF_BVALS, 0, (size_t)ZERO_FLOATS * sizeof(float), stream);
  k_scatter<<<1, 1024, 0, stream>>>(dnodes, bvals, BVALS);
  k_encode<<<128, 128, 0, stream>>>(in_tokens, W_enc, b_enc, W_src, b_src, W_pou,
                                    BVALS, WPROJ, FFULL, ZACC);
  k_wpack<<<Bn, 64, 0, stream>>>(ZACC, Wz, bfv, Wf1, Wf2, WPACK);
  k_flat<<<Bn*Fc, 256, 0, stream>>>(WPROJ, FFULL, FLAT);
  if (ws_size >= (size_t)NEED_FLOATS * sizeof(float)) {
    k_projT<<<dim3(Nn/CHUNK, Bn*Fc), 256, 0, stream>>>(K_list, WPROJ, TPART);
    k_projM<<<dim3(Nn/CHUNK, Bn*Fc), 256, 0, stream>>>(M_list, WPROJ, FLAT, SRC);
    k_khat<<<dim3(16, Bn*Fc), 256, 0, stream>>>(TPART, WPROJ, KHAT);
  } else {
    k_project_fb<<<dim3(Nn/CHUNK, Bn*Fc), 256, 0, stream>>>(K_list, M_list, WPROJ, FLAT, KHAT, SRC);
  }
  k_solve<<<Bn, 768, 0, stream>>>(KHAT, SRC, WPACK, u_init, UBUF);
  k_out<<<dim3(Nn/256, Bn), 256, 0, stream>>>(WPROJ, UBUF, out);
}